// Round 2
// baseline (2173.960 us; speedup 1.0000x reference)
//
#include <hip/hip_runtime.h>
#include <cmath>

// ---- problem constants ----
constexpr int BD   = 8;
constexpr int CIN  = 192;
constexpr int HW   = 4096;
constexpr int NIMG = 32768;
constexpr int HID  = 256;
constexpr int NCLS = 8192;
constexpr int NE   = 131072;

#define EPSW 1e-4f
#define ALPHA 0.7905694150420949f    // mp_cat: Cc/sqrt(256)*0.5, Cc=sqrt(640)
#define BETA  1.5811388300841898f    // Cc/sqrt(64)*0.5
#define SILU_INV 1.6778523489932886f // 1/0.596
#define INV_SQRT2 0.7071067811865476f

using bf16x8 = __attribute__((ext_vector_type(8))) __bf16;
using f32x4  = __attribute__((ext_vector_type(4))) float;

__device__ __forceinline__ ushort f2bf(float f) {   // RNE fp32->bf16
  uint u = __float_as_uint(f);
  u = (u + 0x7FFFu + ((u >> 16) & 1u)) >> 16;
  return (ushort)u;
}
__device__ __forceinline__ float bf2f(ushort h) {
  return __uint_as_float(((uint)h) << 16);
}
__device__ __forceinline__ float wave_red_sum(float v) {
  #pragma unroll
  for (int off = 32; off > 0; off >>= 1) v += __shfl_xor(v, off, 64);
  return v;
}

// ---- weight normalization -> bf16: out[r,ooff+f] = w[r,f]/(EPS*sqrt(F)+||w_r||) ----
__global__ void wnorm_k(const float* __restrict__ w, ushort* __restrict__ out,
                        int F, int ostride, int ooff) {
  const int row  = blockIdx.x;
  const int lane = threadIdx.x;
  const float* wr = w + (size_t)row * F;
  float ss = 0.f;
  for (int f = lane; f < F; f += 64) { float v = wr[f]; ss += v * v; }
  ss = wave_red_sum(ss);
  const float scale = 1.0f / (EPSW * sqrtf((float)F) + sqrtf(ss));
  ushort* o = out + (size_t)row * ostride + ooff;
  for (int f = lane; f < F; f += 64) o[f] = f2bf(wr[f] * scale);
}

// ---- per-dst edge counts (both graphs in one pass) ----
__global__ void count_k(const int* __restrict__ d1, const int* __restrict__ d2,
                        float* __restrict__ c1, float* __restrict__ c2, int E) {
  int e = blockIdx.x * 256 + threadIdx.x;
  if (e < E) {
    atomicAdd(&c1[d1[e]], 1.0f);
    atomicAdd(&c2[d2[e]], 1.0f);
  }
}

__global__ void inv_k(float* __restrict__ c, int n) {
  int i = blockIdx.x * 256 + threadIdx.x;
  if (i < n) c[i] = 1.0f / fmaxf(c[i], 1.0f);
}

// ---- x [8,192,64,64] fp32 -> Xin [32768,192] bf16 (transpose+convert) ----
__global__ __launch_bounds__(256) void xt_k(const float* __restrict__ x,
                                            ushort* __restrict__ Xin) {
  __shared__ float T[192 * 65];
  const int b   = blockIdx.x >> 6;
  const int hw0 = (blockIdx.x & 63) * 64;
  const int t   = threadIdx.x;
  const float* xb = x + (size_t)b * CIN * HW;
  for (int idx = t; idx < CIN * 64; idx += 256) {
    int c = idx >> 6, p = idx & 63;
    T[c * 65 + p] = xb[(size_t)c * HW + hw0 + p];
  }
  __syncthreads();
  ushort* ob = Xin + ((size_t)b * HW + hw0) * CIN;
  for (int idx = t; idx < CIN * 64; idx += 256) {
    int p = idx / CIN, c = idx - p * CIN;
    ob[(size_t)p * CIN + c] = f2bf(T[c * 65 + p]);
  }
}

// ---- fp32 -> bf16 convert (n multiple of 1024) ----
__global__ void cvt_k(const float* __restrict__ in, ushort* __restrict__ out) {
  int i4 = (blockIdx.x * 256 + threadIdx.x) * 4;
  float4 v = *(const float4*)(in + i4);
  ushort4 o = { f2bf(v.x), f2bf(v.y), f2bf(v.z), f2bf(v.w) };
  *(ushort4*)(out + i4) = o;
}

// ---- mp_silu: fp32 in -> bf16 out ----
__global__ void silu_k(const float* __restrict__ h, ushort* __restrict__ a) {
  int i4 = (blockIdx.x * 256 + threadIdx.x) * 4;
  float4 v = *(const float4*)(h + i4);
  float4 s;
  s.x = (v.x / (1.0f + __expf(-v.x))) * SILU_INV;
  s.y = (v.y / (1.0f + __expf(-v.y))) * SILU_INV;
  s.z = (v.z / (1.0f + __expf(-v.z))) * SILU_INV;
  s.w = (v.w / (1.0f + __expf(-v.w))) * SILU_INV;
  ushort4 o = { f2bf(s.x), f2bf(s.y), f2bf(s.z), f2bf(s.w) };
  *(ushort4*)(a + i4) = o;
}

// ---- scatter-add of scaled messages (bf16 gather, fp32 atomics) ----
__global__ __launch_bounds__(256) void scatter_k(
    const ushort* __restrict__ Hsrc, const float* __restrict__ EA,
    const int* __restrict__ src, const int* __restrict__ dst,
    float* __restrict__ agg) {
  const int e    = blockIdx.x * 4 + (threadIdx.x >> 6);
  const int lane = threadIdx.x & 63;
  const int s = src[e];
  const int d = dst[e];
  float* out = agg + (size_t)d * 320;
  const ushort* hs = Hsrc + (size_t)s * 256;
  ushort4 hv = *(const ushort4*)(hs + lane * 4);
  atomicAdd(&out[lane * 4 + 0], ALPHA * bf2f(hv.x));
  atomicAdd(&out[lane * 4 + 1], ALPHA * bf2f(hv.y));
  atomicAdd(&out[lane * 4 + 2], ALPHA * bf2f(hv.z));
  atomicAdd(&out[lane * 4 + 3], ALPHA * bf2f(hv.w));
  float ev = EA[(size_t)e * 64 + lane];
  atomicAdd(&out[256 + lane], BETA * ev);
}

// ---- row L2 normalize of (v/sqrt(2)): fp32 in-place + bf16 copy ----
__global__ __launch_bounds__(256) void rownorm_k(float* __restrict__ X,
                                                 ushort* __restrict__ Xb) {
  const int row  = blockIdx.x * 4 + (threadIdx.x >> 6);
  const int lane = threadIdx.x & 63;
  float4 v = *reinterpret_cast<float4*>(&X[(size_t)row * 256 + lane * 4]);
  v.x *= INV_SQRT2; v.y *= INV_SQRT2; v.z *= INV_SQRT2; v.w *= INV_SQRT2;
  float ss = v.x * v.x + v.y * v.y + v.z * v.z + v.w * v.w;
  ss = wave_red_sum(ss);
  const float sc = 1.0f / fmaxf(sqrtf(ss), 1e-12f);
  v.x *= sc; v.y *= sc; v.z *= sc; v.w *= sc;
  *reinterpret_cast<float4*>(&X[(size_t)row * 256 + lane * 4]) = v;
  ushort4 o = { f2bf(v.x), f2bf(v.y), f2bf(v.z), f2bf(v.w) };
  *(ushort4*)(Xb + (size_t)row * 256 + lane * 4) = o;
}

// ---- bf16 MFMA GEMM: C[M,N] = A[M,K] @ B[N,K]^T, tile 128x128, BK=32 ----
// a_mode 0: A bf16 [M,K]
// a_mode 2: k<320 from AF fp32 [M,320] * invc[row]; k>=320 from A bf16 [M,256]
// c_mode 0: C fp32 [M, ldc]   c_mode 1: C[((col>>12)*256 + row)*4096 + (col&4095)]
__device__ __forceinline__ int lds_swz(int row, int kbyte) {
  return ((row << 6) + kbyte) ^ ((row & 7) << 4);
}

__global__ __launch_bounds__(256) void mgemm_k(
    const ushort* __restrict__ A, const float* __restrict__ AF,
    const float* __restrict__ invc, const ushort* __restrict__ B,
    float* __restrict__ C, int K, int ldc, int a_mode, int c_mode) {
  __shared__ ushort As[128 * 32];
  __shared__ ushort Bs[128 * 32];
  const int t    = threadIdx.x;
  const int row0 = blockIdx.x * 128, col0 = blockIdx.y * 128;
  const int srow = t >> 1;            // staging row/col 0..127
  const int skh  = (t & 1) * 16;      // staging k offset (elements)
  const int w    = t >> 6, lane = t & 63;
  const int wr   = (w >> 1) * 64, wc = (w & 1) * 64;
  const int l15  = lane & 15, lk16 = (lane >> 4) * 16; // frag k-chunk byte
  f32x4 acc[4][4] = {};
  const float inv = (a_mode == 2) ? invc[row0 + srow] : 1.0f;

  uint4 ar0, ar1, br0, br1;
  auto packbf = [](float4 a, float4 b) -> uint4 {
    uint4 r;
    r.x = (uint)f2bf(a.x) | ((uint)f2bf(a.y) << 16);
    r.y = (uint)f2bf(a.z) | ((uint)f2bf(a.w) << 16);
    r.z = (uint)f2bf(b.x) | ((uint)f2bf(b.y) << 16);
    r.w = (uint)f2bf(b.z) | ((uint)f2bf(b.w) << 16);
    return r;
  };
  auto loadA = [&](int k0) {
    if (a_mode == 2 && k0 + skh < 320) {
      const float* p = AF + (size_t)(row0 + srow) * 320 + k0 + skh;
      float4 f0 = *(const float4*)(p);
      float4 f1 = *(const float4*)(p + 4);
      float4 f2 = *(const float4*)(p + 8);
      float4 f3 = *(const float4*)(p + 12);
      f0.x *= inv; f0.y *= inv; f0.z *= inv; f0.w *= inv;
      f1.x *= inv; f1.y *= inv; f1.z *= inv; f1.w *= inv;
      f2.x *= inv; f2.y *= inv; f2.z *= inv; f2.w *= inv;
      f3.x *= inv; f3.y *= inv; f3.z *= inv; f3.w *= inv;
      ar0 = packbf(f0, f1); ar1 = packbf(f2, f3);
    } else {
      const ushort* p = (a_mode == 2)
        ? A + (size_t)(row0 + srow) * 256 + (k0 + skh - 320)
        : A + (size_t)(row0 + srow) * K + k0 + skh;
      ar0 = *(const uint4*)(p);
      ar1 = *(const uint4*)(p + 8);
    }
  };
  auto loadB = [&](int k0) {
    const ushort* p = B + (size_t)(col0 + srow) * K + k0 + skh;
    br0 = *(const uint4*)(p);
    br1 = *(const uint4*)(p + 8);
  };

  loadA(0); loadB(0);
  for (int k0 = 0; k0 < K; k0 += 32) {
    __syncthreads();
    *(uint4*)((char*)As + lds_swz(srow, skh * 2))      = ar0;
    *(uint4*)((char*)As + lds_swz(srow, skh * 2 + 16)) = ar1;
    *(uint4*)((char*)Bs + lds_swz(srow, skh * 2))      = br0;
    *(uint4*)((char*)Bs + lds_swz(srow, skh * 2 + 16)) = br1;
    __syncthreads();
    if (k0 + 32 < K) { loadA(k0 + 32); loadB(k0 + 32); }
    bf16x8 af[4], bfr[4];
    #pragma unroll
    for (int m = 0; m < 4; ++m)
      af[m] = *(const bf16x8*)((const char*)As + lds_swz(wr + m * 16 + l15, lk16));
    #pragma unroll
    for (int n = 0; n < 4; ++n)
      bfr[n] = *(const bf16x8*)((const char*)Bs + lds_swz(wc + n * 16 + l15, lk16));
    #pragma unroll
    for (int m = 0; m < 4; ++m)
      #pragma unroll
      for (int n = 0; n < 4; ++n)
        acc[m][n] = __builtin_amdgcn_mfma_f32_16x16x32_bf16(af[m], bfr[n], acc[m][n], 0, 0, 0);
  }

  #pragma unroll
  for (int m = 0; m < 4; ++m) {
    const int rbase = row0 + wr + m * 16 + (lane >> 4) * 4;
    #pragma unroll
    for (int n = 0; n < 4; ++n) {
      const int col = col0 + wc + n * 16 + l15;
      #pragma unroll
      for (int j = 0; j < 4; ++j) {
        const int r = rbase + j;
        if (c_mode == 0)
          C[(size_t)r * ldc + col] = acc[m][n][j];
        else
          C[((size_t)(col >> 12) * 256 + r) * 4096 + (col & 4095)] = acc[m][n][j];
      }
    }
  }
}

extern "C" void kernel_launch(void* const* d_in, const int* in_sizes, int n_in,
                              void* d_out, int out_size, void* d_ws, size_t ws_size,
                              hipStream_t stream) {
  const float* x        = (const float*)d_in[0];
  const float* class_x  = (const float*)d_in[1];
  const float* ea_c2i   = (const float*)d_in[2];
  const float* ea_i2c   = (const float*)d_in[3];
  const float* w_in_img = (const float*)d_in[4];
  const float* w_in_cls = (const float*)d_in[5];
  const float* wl_c2i_1 = (const float*)d_in[6];
  const float* wr_c2i_1 = (const float*)d_in[7];
  const float* wl_i2c_1 = (const float*)d_in[8];
  const float* wr_i2c_1 = (const float*)d_in[9];
  const float* wl_c2i_2 = (const float*)d_in[10];
  const float* wr_c2i_2 = (const float*)d_in[11];
  const float* wl_i2c_2 = (const float*)d_in[12];
  const float* wr_i2c_2 = (const float*)d_in[13];
  const float* w_out_img = (const float*)d_in[14];
  const float* w_out_cls = (const float*)d_in[15];
  const int* src_c2i = (const int*)d_in[16];
  const int* dst_c2i = (const int*)d_in[17];
  const int* src_i2c = (const int*)d_in[18];
  const int* dst_i2c = (const int*)d_in[19];

  float* ws = (float*)d_ws;
  size_t off = 0;
  auto alloc = [&](size_t n) { float* p = ws + off; off += (n + 15) & ~(size_t)15; return p; };

  float* H_img   = alloc((size_t)NIMG * 256);
  float* H_cls   = alloc((size_t)NCLS * 256);
  float* agg_img = alloc((size_t)NIMG * 320);
  float* agg_cls = alloc((size_t)NCLS * 320);
  ushort* A_img   = (ushort*)alloc((size_t)NIMG * 128);   // bf16 [NIMG,256]
  ushort* A_cls   = (ushort*)alloc((size_t)NCLS * 128);
  ushort* Hbf_img = (ushort*)alloc((size_t)NIMG * 128);
  ushort* Hbf_cls = (ushort*)alloc((size_t)NCLS * 128);
  float* inv_img  = alloc(NIMG + NCLS);
  float* inv_cls  = inv_img + NIMG;
  ushort* wn_in_img  = (ushort*)alloc(256 * 96);
  ushort* wn_in_cls  = (ushort*)alloc(256 * 64);
  ushort* wcat0      = (ushort*)alloc(256 * 288);
  ushort* wcat1      = (ushort*)alloc(256 * 288);
  ushort* wcat2      = (ushort*)alloc(256 * 288);
  ushort* wcat3      = (ushort*)alloc(256 * 288);
  ushort* wn_out_img = (ushort*)alloc(256 * 128);
  ushort* wn_out_cls = (ushort*)alloc(256 * 128);
  // aliases (consumed before their hosts are first written)
  ushort* Xin      = (ushort*)agg_img;   // [NIMG,192] bf16
  ushort* class_bf = (ushort*)agg_cls;   // [NCLS,128] bf16

  const dim3 blk(256);

  // ---- weight normalization (bf16 out) ----
  wnorm_k<<<256, 64, 0, stream>>>(w_in_img, wn_in_img, 192, 192, 0);
  wnorm_k<<<256, 64, 0, stream>>>(w_in_cls, wn_in_cls, 128, 128, 0);
  wnorm_k<<<256, 64, 0, stream>>>(wl_c2i_1, wcat0, 320, 576, 0);
  wnorm_k<<<256, 64, 0, stream>>>(wr_c2i_1, wcat0, 256, 576, 320);
  wnorm_k<<<256, 64, 0, stream>>>(wl_i2c_1, wcat1, 320, 576, 0);
  wnorm_k<<<256, 64, 0, stream>>>(wr_i2c_1, wcat1, 256, 576, 320);
  wnorm_k<<<256, 64, 0, stream>>>(wl_c2i_2, wcat2, 320, 576, 0);
  wnorm_k<<<256, 64, 0, stream>>>(wr_c2i_2, wcat2, 256, 576, 320);
  wnorm_k<<<256, 64, 0, stream>>>(wl_i2c_2, wcat3, 320, 576, 0);
  wnorm_k<<<256, 64, 0, stream>>>(wr_i2c_2, wcat3, 256, 576, 320);
  wnorm_k<<<256, 64, 0, stream>>>(w_out_img, wn_out_img, 256, 256, 0);
  wnorm_k<<<256, 64, 0, stream>>>(w_out_cls, wn_out_cls, 256, 256, 0);

  // ---- per-dst counts ----
  hipMemsetAsync(inv_img, 0, (size_t)(NIMG + NCLS) * sizeof(float), stream);
  count_k<<<NE / 256, blk, 0, stream>>>(dst_c2i, dst_i2c, inv_img, inv_cls, NE);
  inv_k<<<(NIMG + NCLS) / 256, blk, 0, stream>>>(inv_img, NIMG + NCLS);

  // ---- input prep + projections ----
  xt_k<<<512, blk, 0, stream>>>(x, Xin);
  cvt_k<<<(NCLS * 128) / 1024, blk, 0, stream>>>(class_x, class_bf);
  mgemm_k<<<dim3(NIMG / 128, 2), blk, 0, stream>>>(Xin, nullptr, nullptr, wn_in_img,
                                                   H_img, 192, 256, 0, 0);
  mgemm_k<<<dim3(NCLS / 128, 2), blk, 0, stream>>>(class_bf, nullptr, nullptr, wn_in_cls,
                                                   H_cls, 128, 256, 0, 0);

  // ---- layers ----
  const ushort* wc2i[2] = {wcat0, wcat2};
  const ushort* wi2c[2] = {wcat1, wcat3};
  for (int l = 0; l < 2; ++l) {
    silu_k<<<(size_t)NIMG * 256 / 1024, blk, 0, stream>>>(H_img, A_img);
    silu_k<<<(size_t)NCLS * 256 / 1024, blk, 0, stream>>>(H_cls, A_cls);

    // cls -> img
    hipMemsetAsync(agg_img, 0, (size_t)NIMG * 320 * sizeof(float), stream);
    scatter_k<<<NE / 4, blk, 0, stream>>>(A_cls, ea_c2i, src_c2i, dst_c2i, agg_img);
    mgemm_k<<<dim3(NIMG / 128, 2), blk, 0, stream>>>(A_img, agg_img, inv_img, wc2i[l],
                                                     H_img, 576, 256, 2, 0);
    rownorm_k<<<NIMG / 4, blk, 0, stream>>>(H_img, Hbf_img);

    // img -> cls (uses pre-layer a_img, already in A_img)
    hipMemsetAsync(agg_cls, 0, (size_t)NCLS * 320 * sizeof(float), stream);
    scatter_k<<<NE / 4, blk, 0, stream>>>(A_img, ea_i2c, src_i2c, dst_i2c, agg_cls);
    mgemm_k<<<dim3(NCLS / 128, 2), blk, 0, stream>>>(A_cls, agg_cls, inv_cls, wi2c[l],
                                                     H_cls, 576, 256, 2, 0);
    rownorm_k<<<NCLS / 4, blk, 0, stream>>>(H_cls, Hbf_cls);
  }

  // ---- output projections ----
  float* out_img = (float*)d_out;
  float* out_cls = (float*)d_out + (size_t)NIMG * 256;
  // img: swapped orientation (A=W 256xK, B=H) so NCHW store is coalesced
  mgemm_k<<<dim3(2, NIMG / 128), blk, 0, stream>>>(wn_out_img, nullptr, nullptr, Hbf_img,
                                                   out_img, 256, 0, 0, 1);
  mgemm_k<<<dim3(NCLS / 128, 2), blk, 0, stream>>>(Hbf_cls, nullptr, nullptr, wn_out_cls,
                                                   out_cls, 256, 256, 0, 0);
}

// Round 3
// 458.191 us; speedup vs baseline: 4.7447x; 4.7447x over previous
//
#include <hip/hip_runtime.h>
#include <cmath>

// ---- problem constants ----
constexpr int BD   = 8;
constexpr int CIN  = 192;
constexpr int HW   = 4096;
constexpr int NIMG = 32768;
constexpr int HID  = 256;
constexpr int NCLS = 8192;
constexpr int NE   = 131072;

#define EPSW 1e-4f
#define ALPHA 0.7905694150420949f    // mp_cat: Cc/sqrt(256)*0.5, Cc=sqrt(640)
#define BETA  1.5811388300841898f    // Cc/sqrt(64)*0.5
#define SILU_INV 1.6778523489932886f // 1/0.596
#define INV_SQRT2 0.7071067811865476f

using bf16x8 = __attribute__((ext_vector_type(8))) __bf16;
using f32x4  = __attribute__((ext_vector_type(4))) float;

__device__ __forceinline__ ushort f2bf(float f) {   // RNE fp32->bf16
  uint u = __float_as_uint(f);
  u = (u + 0x7FFFu + ((u >> 16) & 1u)) >> 16;
  return (ushort)u;
}
__device__ __forceinline__ float bf2f(ushort h) {
  return __uint_as_float(((uint)h) << 16);
}
__device__ __forceinline__ float wave_red_sum(float v) {
  #pragma unroll
  for (int off = 32; off > 0; off >>= 1) v += __shfl_xor(v, off, 64);
  return v;
}

// ---- weight normalization -> bf16 ----
__global__ void wnorm_k(const float* __restrict__ w, ushort* __restrict__ out,
                        int F, int ostride, int ooff) {
  const int row  = blockIdx.x;
  const int lane = threadIdx.x;
  const float* wr = w + (size_t)row * F;
  float ss = 0.f;
  for (int f = lane; f < F; f += 64) { float v = wr[f]; ss += v * v; }
  ss = wave_red_sum(ss);
  const float scale = 1.0f / (EPSW * sqrtf((float)F) + sqrtf(ss));
  ushort* o = out + (size_t)row * ostride + ooff;
  for (int f = lane; f < F; f += 64) o[f] = f2bf(wr[f] * scale);
}

// ---- CSR build: int counts for both graphs ----
__global__ void counti_k(const int* __restrict__ d1, const int* __restrict__ d2,
                         int* __restrict__ c1, int* __restrict__ c2) {
  int e = blockIdx.x * 256 + threadIdx.x;
  atomicAdd(&c1[d1[e]], 1);
  atomicAdd(&c2[d2[e]], 1);
}

// exclusive scan; block 0 -> (c1,s1,n1), block 1 -> (c2,s2,n2). n multiple of 1024.
__global__ __launch_bounds__(1024) void scan_k(const int* __restrict__ c1, int* __restrict__ s1,
                                               int n1, const int* __restrict__ c2,
                                               int* __restrict__ s2, int n2) {
  __shared__ int tmp[1024];
  __shared__ int carry;
  const int* c = blockIdx.x ? c2 : c1;
  int* s = blockIdx.x ? s2 : s1;
  const int n = blockIdx.x ? n2 : n1;
  const int t = threadIdx.x;
  if (t == 0) carry = 0;
  __syncthreads();
  for (int base = 0; base < n; base += 1024) {
    int v = c[base + t];
    tmp[t] = v;
    __syncthreads();
    #pragma unroll
    for (int off = 1; off < 1024; off <<= 1) {
      int u = (t >= off) ? tmp[t - off] : 0;
      __syncthreads();
      tmp[t] += u;
      __syncthreads();
    }
    s[base + t] = carry + tmp[t] - v;
    __syncthreads();
    if (t == 1023) carry += tmp[1023];
    __syncthreads();
  }
  if (t == 0) s[n] = carry;
}

__global__ void fill_k(const int* __restrict__ dst, const int* __restrict__ start,
                       int* __restrict__ cursor, int* __restrict__ eix) {
  int e = blockIdx.x * 256 + threadIdx.x;
  int d = dst[e];
  int p = atomicAdd(&cursor[d], 1);
  eix[start[d] + p] = e;
}

// ---- x [8,192,64,64] fp32 -> Xin [32768,192] bf16 (transpose+convert) ----
__global__ __launch_bounds__(256) void xt_k(const float* __restrict__ x,
                                            ushort* __restrict__ Xin) {
  __shared__ float T[192 * 65];
  const int b   = blockIdx.x >> 6;
  const int hw0 = (blockIdx.x & 63) * 64;
  const int t   = threadIdx.x;
  const float* xb = x + (size_t)b * CIN * HW;
  for (int idx = t; idx < CIN * 64; idx += 256) {
    int c = idx >> 6, p = idx & 63;
    T[c * 65 + p] = xb[(size_t)c * HW + hw0 + p];
  }
  __syncthreads();
  ushort* ob = Xin + ((size_t)b * HW + hw0) * CIN;
  for (int idx = t; idx < CIN * 64; idx += 256) {
    int p = idx / CIN, c = idx - p * CIN;
    ob[(size_t)p * CIN + c] = f2bf(T[c * 65 + p]);
  }
}

// ---- fp32 -> bf16 convert (n multiple of 1024) ----
__global__ void cvt_k(const float* __restrict__ in, ushort* __restrict__ out) {
  int i4 = (blockIdx.x * 256 + threadIdx.x) * 4;
  float4 v = *(const float4*)(in + i4);
  ushort4 o = { f2bf(v.x), f2bf(v.y), f2bf(v.z), f2bf(v.w) };
  *(ushort4*)(out + i4) = o;
}

// ---- mp_silu: fp32 in -> bf16 out ----
__global__ void silu_k(const float* __restrict__ h, ushort* __restrict__ a) {
  int i4 = (blockIdx.x * 256 + threadIdx.x) * 4;
  float4 v = *(const float4*)(h + i4);
  float4 s;
  s.x = (v.x / (1.0f + __expf(-v.x))) * SILU_INV;
  s.y = (v.y / (1.0f + __expf(-v.y))) * SILU_INV;
  s.z = (v.z / (1.0f + __expf(-v.z))) * SILU_INV;
  s.w = (v.w / (1.0f + __expf(-v.w))) * SILU_INV;
  ushort4 o = { f2bf(s.x), f2bf(s.y), f2bf(s.z), f2bf(s.w) };
  *(ushort4*)(a + i4) = o;
}

// ---- CSR gather-mean: agg[row,320] bf16 = mean over edges of [ALPHA*H[src] | BETA*EA[e]] ----
__global__ __launch_bounds__(256) void agg_k(
    const ushort* __restrict__ Hsrc, const ushort* __restrict__ EA,
    const int* __restrict__ src, const int* __restrict__ eix,
    const int* __restrict__ start, ushort* __restrict__ agg) {
  const int row  = blockIdx.x * 4 + (threadIdx.x >> 6);
  const int lane = threadIdx.x & 63;
  const int s0 = start[row], s1 = start[row + 1];
  float a0 = 0, a1 = 0, a2 = 0, a3 = 0, ae = 0;
  for (int j = s0; j < s1; ++j) {
    const int e = eix[j];
    const int s = src[e];
    ushort4 hv = *(const ushort4*)(Hsrc + (size_t)s * 256 + lane * 4);
    a0 += bf2f(hv.x); a1 += bf2f(hv.y); a2 += bf2f(hv.z); a3 += bf2f(hv.w);
    ae += bf2f(EA[(size_t)e * 64 + lane]);
  }
  const float inv = 1.0f / fmaxf((float)(s1 - s0), 1.0f);
  const float ca = ALPHA * inv, cb = BETA * inv;
  ushort* orow = agg + (size_t)row * 320;
  ushort4 o = { f2bf(a0 * ca), f2bf(a1 * ca), f2bf(a2 * ca), f2bf(a3 * ca) };
  *(ushort4*)(orow + lane * 4) = o;
  orow[256 + lane] = f2bf(ae * cb);
}

// ---- row L2 normalize of (v/sqrt(2)): fp32 in-place + bf16 copy ----
__global__ __launch_bounds__(256) void rownorm_k(float* __restrict__ X,
                                                 ushort* __restrict__ Xb) {
  const int row  = blockIdx.x * 4 + (threadIdx.x >> 6);
  const int lane = threadIdx.x & 63;
  float4 v = *reinterpret_cast<float4*>(&X[(size_t)row * 256 + lane * 4]);
  v.x *= INV_SQRT2; v.y *= INV_SQRT2; v.z *= INV_SQRT2; v.w *= INV_SQRT2;
  float ss = v.x * v.x + v.y * v.y + v.z * v.z + v.w * v.w;
  ss = wave_red_sum(ss);
  const float sc = 1.0f / fmaxf(sqrtf(ss), 1e-12f);
  v.x *= sc; v.y *= sc; v.z *= sc; v.w *= sc;
  *reinterpret_cast<float4*>(&X[(size_t)row * 256 + lane * 4]) = v;
  ushort4 o = { f2bf(v.x), f2bf(v.y), f2bf(v.z), f2bf(v.w) };
  *(ushort4*)(Xb + (size_t)row * 256 + lane * 4) = o;
}

// ---- bf16 MFMA GEMM: C[M,N] = A[M,K] @ B[N,K]^T, tile 128x128, BK=32 ----
// a_mode 0: A bf16 [M,K]
// a_mode 2: k<320 from AG bf16 [M,320]; k>=320 from A bf16 [M,256]
// c_mode 0: C fp32 [M, ldc]   c_mode 1: C[((col>>12)*256 + row)*4096 + (col&4095)]
__device__ __forceinline__ int lds_swz(int row, int kbyte) {
  return ((row << 6) + kbyte) ^ ((row & 7) << 4);
}

__global__ __launch_bounds__(256) void mgemm_k(
    const ushort* __restrict__ A, const ushort* __restrict__ AG,
    const ushort* __restrict__ B, float* __restrict__ C,
    int K, int ldc, int a_mode, int c_mode) {
  __shared__ ushort As[128 * 32];
  __shared__ ushort Bs[128 * 32];
  const int t    = threadIdx.x;
  const int row0 = blockIdx.x * 128, col0 = blockIdx.y * 128;
  const int srow = t >> 1;            // staging row/col 0..127
  const int skh  = (t & 1) * 16;      // staging k offset (elements)
  const int w    = t >> 6, lane = t & 63;
  const int wr   = (w >> 1) * 64, wc = (w & 1) * 64;
  const int l15  = lane & 15, lk16 = (lane >> 4) * 16;
  f32x4 acc[4][4] = {};

  uint4 ar0, ar1, br0, br1;
  auto loadA = [&](int k0) {
    const ushort* p;
    if (a_mode == 2) {
      int kk = k0 + skh;
      p = (kk < 320) ? AG + (size_t)(row0 + srow) * 320 + kk
                     : A + (size_t)(row0 + srow) * 256 + (kk - 320);
    } else {
      p = A + (size_t)(row0 + srow) * K + k0 + skh;
    }
    ar0 = *(const uint4*)(p);
    ar1 = *(const uint4*)(p + 8);
  };
  auto loadB = [&](int k0) {
    const ushort* p = B + (size_t)(col0 + srow) * K + k0 + skh;
    br0 = *(const uint4*)(p);
    br1 = *(const uint4*)(p + 8);
  };

  loadA(0); loadB(0);
  for (int k0 = 0; k0 < K; k0 += 32) {
    __syncthreads();
    *(uint4*)((char*)As + lds_swz(srow, skh * 2))      = ar0;
    *(uint4*)((char*)As + lds_swz(srow, skh * 2 + 16)) = ar1;
    *(uint4*)((char*)Bs + lds_swz(srow, skh * 2))      = br0;
    *(uint4*)((char*)Bs + lds_swz(srow, skh * 2 + 16)) = br1;
    __syncthreads();
    if (k0 + 32 < K) { loadA(k0 + 32); loadB(k0 + 32); }
    bf16x8 af[4], bfr[4];
    #pragma unroll
    for (int m = 0; m < 4; ++m)
      af[m] = *(const bf16x8*)((const char*)As + lds_swz(wr + m * 16 + l15, lk16));
    #pragma unroll
    for (int n = 0; n < 4; ++n)
      bfr[n] = *(const bf16x8*)((const char*)Bs + lds_swz(wc + n * 16 + l15, lk16));
    #pragma unroll
    for (int m = 0; m < 4; ++m)
      #pragma unroll
      for (int n = 0; n < 4; ++n)
        acc[m][n] = __builtin_amdgcn_mfma_f32_16x16x32_bf16(af[m], bfr[n], acc[m][n], 0, 0, 0);
  }

  #pragma unroll
  for (int m = 0; m < 4; ++m) {
    const int rbase = row0 + wr + m * 16 + (lane >> 4) * 4;
    #pragma unroll
    for (int n = 0; n < 4; ++n) {
      const int col = col0 + wc + n * 16 + l15;
      #pragma unroll
      for (int j = 0; j < 4; ++j) {
        const int r = rbase + j;
        if (c_mode == 0)
          C[(size_t)r * ldc + col] = acc[m][n][j];
        else
          C[((size_t)(col >> 12) * 256 + r) * 4096 + (col & 4095)] = acc[m][n][j];
      }
    }
  }
}

extern "C" void kernel_launch(void* const* d_in, const int* in_sizes, int n_in,
                              void* d_out, int out_size, void* d_ws, size_t ws_size,
                              hipStream_t stream) {
  const float* x        = (const float*)d_in[0];
  const float* class_x  = (const float*)d_in[1];
  const float* ea_c2i   = (const float*)d_in[2];
  const float* ea_i2c   = (const float*)d_in[3];
  const float* w_in_img = (const float*)d_in[4];
  const float* w_in_cls = (const float*)d_in[5];
  const float* wl_c2i_1 = (const float*)d_in[6];
  const float* wr_c2i_1 = (const float*)d_in[7];
  const float* wl_i2c_1 = (const float*)d_in[8];
  const float* wr_i2c_1 = (const float*)d_in[9];
  const float* wl_c2i_2 = (const float*)d_in[10];
  const float* wr_c2i_2 = (const float*)d_in[11];
  const float* wl_i2c_2 = (const float*)d_in[12];
  const float* wr_i2c_2 = (const float*)d_in[13];
  const float* w_out_img = (const float*)d_in[14];
  const float* w_out_cls = (const float*)d_in[15];
  const int* src_c2i = (const int*)d_in[16];
  const int* dst_c2i = (const int*)d_in[17];
  const int* src_i2c = (const int*)d_in[18];
  const int* dst_i2c = (const int*)d_in[19];

  float* ws = (float*)d_ws;
  size_t off = 0;
  auto alloc = [&](size_t n) { float* p = ws + off; off += (n + 15) & ~(size_t)15; return p; };

  float* H_img    = alloc((size_t)NIMG * 256);
  float* H_cls    = alloc((size_t)NCLS * 256);
  ushort* A_img   = (ushort*)alloc((size_t)NIMG * 128);   // bf16 [NIMG,256]
  ushort* A_cls   = (ushort*)alloc((size_t)NCLS * 128);
  ushort* Hbf_img = (ushort*)alloc((size_t)NIMG * 128);
  ushort* Hbf_cls = (ushort*)alloc((size_t)NCLS * 128);
  ushort* agg_img = (ushort*)alloc((size_t)NIMG * 160);   // bf16 [NIMG,320]
  ushort* agg_cls = (ushort*)alloc((size_t)NCLS * 160);
  ushort* ea_c2i_bf = (ushort*)alloc((size_t)NE * 32);    // bf16 [NE,64]
  ushort* ea_i2c_bf = (ushort*)alloc((size_t)NE * 32);
  int* cnt_img   = (int*)alloc(NIMG + NCLS);
  int* cnt_cls   = cnt_img + NIMG;
  int* cur_img   = (int*)alloc(NIMG + NCLS);
  int* cur_cls   = cur_img + NIMG;
  int* start_img = (int*)alloc(NIMG + 1 + NCLS + 1 + 14);
  int* start_cls = start_img + NIMG + 1;
  int* eix_c2i   = (int*)alloc(NE);
  int* eix_i2c   = (int*)alloc(NE);
  ushort* wn_in_img  = (ushort*)alloc(256 * 96);
  ushort* wn_in_cls  = (ushort*)alloc(256 * 64);
  ushort* wcat0      = (ushort*)alloc(256 * 288);
  ushort* wcat1      = (ushort*)alloc(256 * 288);
  ushort* wcat2      = (ushort*)alloc(256 * 288);
  ushort* wcat3      = (ushort*)alloc(256 * 288);
  ushort* wn_out_img = (ushort*)alloc(256 * 128);
  ushort* wn_out_cls = (ushort*)alloc(256 * 128);
  // aliases: consumed by input GEMMs before layer-1 agg_k overwrites hosts
  ushort* Xin      = agg_img;   // [NIMG,192] bf16 (needs 6.3M <= 10.5M ushorts)
  ushort* class_bf = agg_cls;   // [NCLS,128] bf16

  const dim3 blk(256);

  // ---- CSR build ----
  hipMemsetAsync(cnt_img, 0, (size_t)(NIMG + NCLS) * sizeof(int), stream);
  hipMemsetAsync(cur_img, 0, (size_t)(NIMG + NCLS) * sizeof(int), stream);
  counti_k<<<NE / 256, blk, 0, stream>>>(dst_c2i, dst_i2c, cnt_img, cnt_cls);
  scan_k<<<2, 1024, 0, stream>>>(cnt_img, start_img, NIMG, cnt_cls, start_cls, NCLS);
  fill_k<<<NE / 256, blk, 0, stream>>>(dst_c2i, start_img, cur_img, eix_c2i);
  fill_k<<<NE / 256, blk, 0, stream>>>(dst_i2c, start_cls, cur_cls, eix_i2c);

  // ---- weight normalization (bf16 out) ----
  wnorm_k<<<256, 64, 0, stream>>>(w_in_img, wn_in_img, 192, 192, 0);
  wnorm_k<<<256, 64, 0, stream>>>(w_in_cls, wn_in_cls, 128, 128, 0);
  wnorm_k<<<256, 64, 0, stream>>>(wl_c2i_1, wcat0, 320, 576, 0);
  wnorm_k<<<256, 64, 0, stream>>>(wr_c2i_1, wcat0, 256, 576, 320);
  wnorm_k<<<256, 64, 0, stream>>>(wl_i2c_1, wcat1, 320, 576, 0);
  wnorm_k<<<256, 64, 0, stream>>>(wr_i2c_1, wcat1, 256, 576, 320);
  wnorm_k<<<256, 64, 0, stream>>>(wl_c2i_2, wcat2, 320, 576, 0);
  wnorm_k<<<256, 64, 0, stream>>>(wr_c2i_2, wcat2, 256, 576, 320);
  wnorm_k<<<256, 64, 0, stream>>>(wl_i2c_2, wcat3, 320, 576, 0);
  wnorm_k<<<256, 64, 0, stream>>>(wr_i2c_2, wcat3, 256, 576, 320);
  wnorm_k<<<256, 64, 0, stream>>>(w_out_img, wn_out_img, 256, 256, 0);
  wnorm_k<<<256, 64, 0, stream>>>(w_out_cls, wn_out_cls, 256, 256, 0);

  // ---- input prep + projections ----
  cvt_k<<<(NE * 64) / 1024, blk, 0, stream>>>(ea_c2i, ea_c2i_bf);
  cvt_k<<<(NE * 64) / 1024, blk, 0, stream>>>(ea_i2c, ea_i2c_bf);
  xt_k<<<512, blk, 0, stream>>>(x, Xin);
  cvt_k<<<(NCLS * 128) / 1024, blk, 0, stream>>>(class_x, class_bf);
  mgemm_k<<<dim3(NIMG / 128, 2), blk, 0, stream>>>(Xin, nullptr, wn_in_img,
                                                   H_img, 192, 256, 0, 0);
  mgemm_k<<<dim3(NCLS / 128, 2), blk, 0, stream>>>(class_bf, nullptr, wn_in_cls,
                                                   H_cls, 128, 256, 0, 0);

  // ---- layers ----
  const ushort* wc2i[2] = {wcat0, wcat2};
  const ushort* wi2c[2] = {wcat1, wcat3};
  for (int l = 0; l < 2; ++l) {
    silu_k<<<(size_t)NIMG * 256 / 1024, blk, 0, stream>>>(H_img, A_img);
    silu_k<<<(size_t)NCLS * 256 / 1024, blk, 0, stream>>>(H_cls, A_cls);

    // cls -> img
    agg_k<<<NIMG / 4, blk, 0, stream>>>(A_cls, ea_c2i_bf, src_c2i, eix_c2i,
                                        start_img, agg_img);
    mgemm_k<<<dim3(NIMG / 128, 2), blk, 0, stream>>>(A_img, agg_img, wc2i[l],
                                                     H_img, 576, 256, 2, 0);
    rownorm_k<<<NIMG / 4, blk, 0, stream>>>(H_img, Hbf_img);

    // img -> cls (uses pre-layer a_img, already in A_img)
    agg_k<<<NCLS / 4, blk, 0, stream>>>(A_img, ea_i2c_bf, src_i2c, eix_i2c,
                                        start_cls, agg_cls);
    mgemm_k<<<dim3(NCLS / 128, 2), blk, 0, stream>>>(A_cls, agg_cls, wi2c[l],
                                                     H_cls, 576, 256, 2, 0);
    rownorm_k<<<NCLS / 4, blk, 0, stream>>>(H_cls, Hbf_cls);
  }

  // ---- output projections ----
  float* out_img = (float*)d_out;
  float* out_cls = (float*)d_out + (size_t)NIMG * 256;
  // img: swapped orientation (A=W 256xK, B=H) so NCHW store is coalesced
  mgemm_k<<<dim3(2, NIMG / 128), blk, 0, stream>>>(wn_out_img, nullptr, Hbf_img,
                                                   out_img, 256, 0, 0, 1);
  mgemm_k<<<dim3(NCLS / 128, 2), blk, 0, stream>>>(Hbf_cls, nullptr, wn_out_cls,
                                                   out_cls, 256, 256, 0, 0);
}

// Round 4
// 312.722 us; speedup vs baseline: 6.9517x; 1.4652x over previous
//
#include <hip/hip_runtime.h>
#include <cmath>

// ---- problem constants ----
constexpr int BD   = 8;
constexpr int CIN  = 192;
constexpr int HW   = 4096;
constexpr int NIMG = 32768;
constexpr int HID  = 256;
constexpr int NCLS = 8192;
constexpr int NE   = 131072;

#define EPSW 1e-4f
#define ALPHA 0.7905694150420949f    // mp_cat: Cc/sqrt(256)*0.5, Cc=sqrt(640)
#define BETA  1.5811388300841898f    // Cc/sqrt(64)*0.5
#define SILU_INV 1.6778523489932886f // 1/0.596

using bf16x8 = __attribute__((ext_vector_type(8))) __bf16;
using f32x4  = __attribute__((ext_vector_type(4))) float;

__device__ __forceinline__ ushort f2bf(float f) {   // RNE fp32->bf16
  uint u = __float_as_uint(f);
  u = (u + 0x7FFFu + ((u >> 16) & 1u)) >> 16;
  return (ushort)u;
}
__device__ __forceinline__ float bf2f(ushort h) {
  return __uint_as_float(((uint)h) << 16);
}
__device__ __forceinline__ float bflo(uint u) { return __uint_as_float(u << 16); }
__device__ __forceinline__ float bfhi(uint u) { return __uint_as_float(u & 0xFFFF0000u); }
__device__ __forceinline__ uint bfpack(float lo, float hi) {
  return (uint)f2bf(lo) | ((uint)f2bf(hi) << 16);
}
__device__ __forceinline__ float wave_red_sum(float v) {
  #pragma unroll
  for (int off = 32; off > 0; off >>= 1) v += __shfl_xor(v, off, 64);
  return v;
}
__device__ __forceinline__ int wave_red_sumi(int v) {
  #pragma unroll
  for (int off = 32; off > 0; off >>= 1) v += __shfl_xor(v, off, 64);
  return v;
}

// ---- batched weight normalization -> bf16 ----
struct WNA {
  const float* w[12];
  ushort* o[12];
  int F[12];
  int os[12];
  int oo[12];
};
__global__ void wnorm_all_k(WNA a) {
  const int wi = blockIdx.y, row = blockIdx.x, lane = threadIdx.x;
  const int F = a.F[wi];
  const float* wr = a.w[wi] + (size_t)row * F;
  float ss = 0.f;
  for (int f = lane; f < F; f += 64) { float v = wr[f]; ss += v * v; }
  ss = wave_red_sum(ss);
  const float scale = 1.0f / (EPSW * sqrtf((float)F) + sqrtf(ss));
  ushort* o = a.o[wi] + (size_t)row * a.os[wi] + a.oo[wi];
  for (int f = lane; f < F; f += 64) o[f] = f2bf(wr[f] * scale);
}

// ---- CSR build ----
__global__ void counti_k(const int* __restrict__ d1, const int* __restrict__ d2,
                         int* __restrict__ c1, int* __restrict__ c2) {
  int e = blockIdx.x * 256 + threadIdx.x;
  atomicAdd(&c1[d1[e]], 1);
  atomicAdd(&c2[d2[e]], 1);
}

// blocks 0..31: img counts, 32..39: cls. Each block scans 1024 ints.
__global__ __launch_bounds__(256) void scanA_k(const int* __restrict__ cnt,
                                               int* __restrict__ st_img,
                                               int* __restrict__ st_cls,
                                               int* __restrict__ bsum) {
  const int bid = blockIdx.x;
  const bool cls = bid >= 32;
  const int* c = cnt + (cls ? NIMG : 0);
  int* s = cls ? st_cls : st_img;
  const int base = (cls ? bid - 32 : bid) * 1024;
  const int t = threadIdx.x, lane = t & 63, wid = t >> 6;
  int4 v = *(const int4*)(c + base + t * 4);
  const int i0 = v.x, i1 = i0 + v.y, i2 = i1 + v.z, i3 = i2 + v.w;
  int x = i3;
  #pragma unroll
  for (int off = 1; off < 64; off <<= 1) {
    int y = __shfl_up(x, off, 64);
    if (lane >= off) x += y;
  }
  const int pre = x - i3;                 // wave-exclusive prefix of thread totals
  __shared__ int wt[4];
  if (lane == 63) wt[wid] = x;
  __syncthreads();
  int woff = 0;
  #pragma unroll
  for (int i = 0; i < 4; ++i) if (i < wid) woff += wt[i];
  const int b = woff + pre;
  int4 o = { b, b + i0, b + i1, b + i2 };
  *(int4*)(s + base + t * 4) = o;
  if (t == 255) bsum[bid] = woff + x;
}

// add predecessor block sums (within segment); write sentinels.
__global__ __launch_bounds__(256) void scanC_k(const int* __restrict__ bsum,
                                               int* __restrict__ st_img,
                                               int* __restrict__ st_cls) {
  const int bid = blockIdx.x;
  const bool cls = bid >= 32;
  const int seg0 = cls ? 32 : 0;
  const int t = threadIdx.x;
  __shared__ int off_s;
  if (t < 64) {
    int v = (t < bid - seg0) ? bsum[seg0 + t] : 0;
    v = wave_red_sumi(v);
    if (t == 0) off_s = v;
  }
  __syncthreads();
  const int off = off_s;
  int* s = cls ? st_cls : st_img;
  const int base = (cls ? bid - 32 : bid) * 1024;
  int4 v = *(int4*)(s + base + t * 4);
  v.x += off; v.y += off; v.z += off; v.w += off;
  *(int4*)(s + base + t * 4) = v;
  if (bid == 0 && t == 0) { st_img[NIMG] = NE; st_cls[NCLS] = NE; }
}

__global__ void fill2_k(const int* __restrict__ dst1, const int* __restrict__ src1,
                        const int* __restrict__ st1, int* __restrict__ cur1,
                        int2* __restrict__ eix1,
                        const int* __restrict__ dst2, const int* __restrict__ src2,
                        const int* __restrict__ st2, int* __restrict__ cur2,
                        int2* __restrict__ eix2) {
  int e = blockIdx.x * 256 + threadIdx.x;
  int d = dst1[e];
  int p = atomicAdd(&cur1[d], 1);
  eix1[st1[d] + p] = make_int2(e, src1[e]);
  d = dst2[e];
  p = atomicAdd(&cur2[d], 1);
  eix2[st2[d] + p] = make_int2(e, src2[e]);
}

// ---- x [8,192,64,64] fp32 -> Xin [32768,192] bf16 (transpose+convert) ----
__global__ __launch_bounds__(256) void xt_k(const float* __restrict__ x,
                                            ushort* __restrict__ Xin) {
  __shared__ float T[192 * 65];
  const int b   = blockIdx.x >> 6;
  const int hw0 = (blockIdx.x & 63) * 64;
  const int t   = threadIdx.x;
  const float* xb = x + (size_t)b * CIN * HW;
  for (int idx = t; idx < CIN * 64; idx += 256) {
    int c = idx >> 6, p = idx & 63;
    T[c * 65 + p] = xb[(size_t)c * HW + hw0 + p];
  }
  __syncthreads();
  ushort* ob = Xin + ((size_t)b * HW + hw0) * CIN;
  for (int idx = t; idx < CIN * 64; idx += 256) {
    int p = idx / CIN, c = idx - p * CIN;
    ob[(size_t)p * CIN + c] = f2bf(T[c * 65 + p]);
  }
}

// ---- fused fp32->bf16 convert: ea_c2i, ea_i2c, class_x ----
__global__ void cvt3_k(const float* __restrict__ p0, const float* __restrict__ p1,
                       const float* __restrict__ p2, ushort* __restrict__ o0,
                       ushort* __restrict__ o1, ushort* __restrict__ o2) {
  const size_t n0 = (size_t)NE * 64;
  size_t i4 = ((size_t)blockIdx.x * 256 + threadIdx.x) * 4;
  const float* in; ushort* out; size_t idx;
  if (i4 < n0)          { in = p0; out = o0; idx = i4; }
  else if (i4 < 2 * n0) { in = p1; out = o1; idx = i4 - n0; }
  else                  { in = p2; out = o2; idx = i4 - 2 * n0; }
  float4 v = *(const float4*)(in + idx);
  ushort4 o = { f2bf(v.x), f2bf(v.y), f2bf(v.z), f2bf(v.w) };
  *(ushort4*)(out + idx) = o;
}

// ---- fused mp_silu (img + cls), bf16 in -> bf16 out, 8 elems/thread ----
__global__ void silu2_k(const ushort* __restrict__ Hi, const ushort* __restrict__ Hc,
                        ushort* __restrict__ Ai, ushort* __restrict__ Ac) {
  const size_t nimg = (size_t)NIMG * 256;
  size_t i8 = ((size_t)blockIdx.x * 256 + threadIdx.x) * 8;
  const ushort* in; ushort* out; size_t idx;
  if (i8 < nimg) { in = Hi; out = Ai; idx = i8; }
  else           { in = Hc; out = Ac; idx = i8 - nimg; }
  uint4 v = *(const uint4*)(in + idx);
  uint r[4];
  uint uu[4] = { v.x, v.y, v.z, v.w };
  #pragma unroll
  for (int i = 0; i < 4; ++i) {
    float lo = bflo(uu[i]), hi = bfhi(uu[i]);
    lo = (lo / (1.0f + __expf(-lo))) * SILU_INV;
    hi = (hi / (1.0f + __expf(-hi))) * SILU_INV;
    r[i] = bfpack(lo, hi);
  }
  uint4 o = { r[0], r[1], r[2], r[3] };
  *(uint4*)(out + idx) = o;
}

// ---- fused CSR gather-mean (img rows then cls rows), bf16 out ----
__global__ __launch_bounds__(256) void agg2_k(
    const ushort* __restrict__ Aimg, const ushort* __restrict__ Acls,
    const ushort* __restrict__ ea_ci, const ushort* __restrict__ ea_ic,
    const int2* __restrict__ eix_ci, const int2* __restrict__ eix_ic,
    const int* __restrict__ st_img, const int* __restrict__ st_cls,
    ushort* __restrict__ agg_img, ushort* __restrict__ agg_cls) {
  const int row  = blockIdx.x * 4 + (threadIdx.x >> 6);
  const int lane = threadIdx.x & 63;
  const ushort* Hs; const ushort* EA; const int2* eix; const int* st; ushort* out;
  int r;
  if (row < NIMG) { r = row;        Hs = Acls; EA = ea_ci; eix = eix_ci; st = st_img;
                    out = agg_img + (size_t)r * 320; }
  else            { r = row - NIMG; Hs = Aimg; EA = ea_ic; eix = eix_ic; st = st_cls;
                    out = agg_cls + (size_t)r * 320; }
  const int s0 = st[r], s1 = st[r + 1];
  float a0 = 0, a1 = 0, a2 = 0, a3 = 0, ae = 0;
  for (int j = s0; j < s1; ++j) {
    const int2 es = eix[j];
    ushort4 hv = *(const ushort4*)(Hs + (size_t)es.y * 256 + lane * 4);
    a0 += bf2f(hv.x); a1 += bf2f(hv.y); a2 += bf2f(hv.z); a3 += bf2f(hv.w);
    ae += bf2f(EA[(size_t)es.x * 64 + lane]);
  }
  const float inv = 1.0f / fmaxf((float)(s1 - s0), 1.0f);
  const float ca = ALPHA * inv, cb = BETA * inv;
  ushort4 o = { f2bf(a0 * ca), f2bf(a1 * ca), f2bf(a2 * ca), f2bf(a3 * ca) };
  *(ushort4*)(out + lane * 4) = o;
  out[256 + lane] = f2bf(ae * cb);
}

// ---- fused row L2 normalize (img + cls), bf16 in-place ----
// (the /sqrt(2) of mp_sum cancels under L2 normalization)
__global__ __launch_bounds__(256) void rownorm2_k(ushort* __restrict__ Hi,
                                                  ushort* __restrict__ Hc) {
  const int row  = blockIdx.x * 4 + (threadIdx.x >> 6);
  const int lane = threadIdx.x & 63;
  ushort* H = (row < NIMG) ? Hi + (size_t)row * 256
                           : Hc + (size_t)(row - NIMG) * 256;
  uint2 v = *(uint2*)(H + lane * 4);
  float x0 = bflo(v.x), x1 = bfhi(v.x), x2 = bflo(v.y), x3 = bfhi(v.y);
  float ss = x0 * x0 + x1 * x1 + x2 * x2 + x3 * x3;
  ss = wave_red_sum(ss);
  const float sc = 1.0f / fmaxf(sqrtf(ss), 1e-12f);
  uint2 o = { bfpack(x0 * sc, x1 * sc), bfpack(x2 * sc, x3 * sc) };
  *(uint2*)(H + lane * 4) = o;
}

// ---- bf16 MFMA GEMM: C[M,N] = A[M,K] @ B[N,K]^T, tile 128x128, BK=32 ----
// a_mode 0: A bf16 [M,K]
// a_mode 2: k<320 from AG bf16 [M,320]; k>=320 from A bf16 [M,256]
// c_mode 0: bf16 [M,ldc]; 1: fp32 img NCHW C[((col>>12)*256+row)*4096+(col&4095)];
// c_mode 2: fp32 [M,ldc]
__device__ __forceinline__ int lds_swz(int row, int kbyte) {
  return ((row << 6) + kbyte) ^ ((row & 7) << 4);
}

__global__ __launch_bounds__(256) void mgemm_k(
    const ushort* __restrict__ A, const ushort* __restrict__ AG,
    const ushort* __restrict__ B, void* __restrict__ Cv,
    int K, int ldc, int a_mode, int c_mode) {
  __shared__ ushort As[128 * 32];
  __shared__ ushort Bs[128 * 32];
  const int t    = threadIdx.x;
  const int row0 = blockIdx.x * 128, col0 = blockIdx.y * 128;
  const int srow = t >> 1;
  const int skh  = (t & 1) * 16;
  const int w    = t >> 6, lane = t & 63;
  const int wr   = (w >> 1) * 64, wc = (w & 1) * 64;
  const int l15  = lane & 15, lk16 = (lane >> 4) * 16;
  f32x4 acc[4][4] = {};

  uint4 ar0, ar1, br0, br1;
  auto loadA = [&](int k0) {
    const ushort* p;
    if (a_mode == 2) {
      int kk = k0 + skh;
      p = (kk < 320) ? AG + (size_t)(row0 + srow) * 320 + kk
                     : A + (size_t)(row0 + srow) * 256 + (kk - 320);
    } else {
      p = A + (size_t)(row0 + srow) * K + k0 + skh;
    }
    ar0 = *(const uint4*)(p);
    ar1 = *(const uint4*)(p + 8);
  };
  auto loadB = [&](int k0) {
    const ushort* p = B + (size_t)(col0 + srow) * K + k0 + skh;
    br0 = *(const uint4*)(p);
    br1 = *(const uint4*)(p + 8);
  };

  loadA(0); loadB(0);
  for (int k0 = 0; k0 < K; k0 += 32) {
    __syncthreads();
    *(uint4*)((char*)As + lds_swz(srow, skh * 2))      = ar0;
    *(uint4*)((char*)As + lds_swz(srow, skh * 2 + 16)) = ar1;
    *(uint4*)((char*)Bs + lds_swz(srow, skh * 2))      = br0;
    *(uint4*)((char*)Bs + lds_swz(srow, skh * 2 + 16)) = br1;
    __syncthreads();
    if (k0 + 32 < K) { loadA(k0 + 32); loadB(k0 + 32); }
    bf16x8 af[4], bfr[4];
    #pragma unroll
    for (int m = 0; m < 4; ++m)
      af[m] = *(const bf16x8*)((const char*)As + lds_swz(wr + m * 16 + l15, lk16));
    #pragma unroll
    for (int n = 0; n < 4; ++n)
      bfr[n] = *(const bf16x8*)((const char*)Bs + lds_swz(wc + n * 16 + l15, lk16));
    #pragma unroll
    for (int m = 0; m < 4; ++m)
      #pragma unroll
      for (int n = 0; n < 4; ++n)
        acc[m][n] = __builtin_amdgcn_mfma_f32_16x16x32_bf16(af[m], bfr[n], acc[m][n], 0, 0, 0);
  }

  ushort* Cb = (ushort*)Cv;
  float*  Cf = (float*)Cv;
  #pragma unroll
  for (int m = 0; m < 4; ++m) {
    const int rbase = row0 + wr + m * 16 + (lane >> 4) * 4;
    #pragma unroll
    for (int n = 0; n < 4; ++n) {
      const int col = col0 + wc + n * 16 + l15;
      #pragma unroll
      for (int j = 0; j < 4; ++j) {
        const int r = rbase + j;
        if (c_mode == 0)
          Cb[(size_t)r * ldc + col] = f2bf(acc[m][n][j]);
        else if (c_mode == 1)
          Cf[((size_t)(col >> 12) * 256 + r) * 4096 + (col & 4095)] = acc[m][n][j];
        else
          Cf[(size_t)r * ldc + col] = acc[m][n][j];
      }
    }
  }
}

extern "C" void kernel_launch(void* const* d_in, const int* in_sizes, int n_in,
                              void* d_out, int out_size, void* d_ws, size_t ws_size,
                              hipStream_t stream) {
  const float* x        = (const float*)d_in[0];
  const float* class_x  = (const float*)d_in[1];
  const float* ea_c2i   = (const float*)d_in[2];
  const float* ea_i2c   = (const float*)d_in[3];
  const int* src_c2i = (const int*)d_in[16];
  const int* dst_c2i = (const int*)d_in[17];
  const int* src_i2c = (const int*)d_in[18];
  const int* dst_i2c = (const int*)d_in[19];

  float* ws = (float*)d_ws;
  size_t off = 0;
  auto alloc = [&](size_t n) { float* p = ws + off; off += (n + 15) & ~(size_t)15; return p; };

  ushort* H_img   = (ushort*)alloc((size_t)NIMG * 128);   // bf16 [NIMG,256]
  ushort* H_cls   = (ushort*)alloc((size_t)NCLS * 128);
  ushort* A_img   = (ushort*)alloc((size_t)NIMG * 128);
  ushort* A_cls   = (ushort*)alloc((size_t)NCLS * 128);
  ushort* agg_img = (ushort*)alloc((size_t)NIMG * 160);   // bf16 [NIMG,320]
  ushort* agg_cls = (ushort*)alloc((size_t)NCLS * 160);
  ushort* ea_c2i_bf = (ushort*)alloc((size_t)NE * 32);    // bf16 [NE,64]
  ushort* ea_i2c_bf = (ushort*)alloc((size_t)NE * 32);
  int* cnt       = (int*)alloc(2 * (NIMG + NCLS));        // cnt | cur (one memset)
  int* cur       = cnt + (NIMG + NCLS);
  int* bsum      = (int*)alloc(48);
  int* st_img    = (int*)alloc(NIMG + 1 + NCLS + 1 + 14);
  int* st_cls    = st_img + NIMG + 1;
  int2* eix_c2i  = (int2*)alloc((size_t)NE * 2);
  int2* eix_i2c  = (int2*)alloc((size_t)NE * 2);
  ushort* wn_in_img  = (ushort*)alloc(256 * 96);
  ushort* wn_in_cls  = (ushort*)alloc(256 * 64);
  ushort* wcat0      = (ushort*)alloc(256 * 288);
  ushort* wcat1      = (ushort*)alloc(256 * 288);
  ushort* wcat2      = (ushort*)alloc(256 * 288);
  ushort* wcat3      = (ushort*)alloc(256 * 288);
  ushort* wn_out_img = (ushort*)alloc(256 * 128);
  ushort* wn_out_cls = (ushort*)alloc(256 * 128);
  // aliases: consumed by input GEMMs before layer-1 agg2_k overwrites hosts
  ushort* Xin      = agg_img;   // [NIMG,192] bf16
  ushort* class_bf = agg_cls;   // [NCLS,128] bf16

  const dim3 blk(256);

  // ---- CSR build ----
  hipMemsetAsync(cnt, 0, (size_t)2 * (NIMG + NCLS) * sizeof(int), stream);
  counti_k<<<NE / 256, blk, 0, stream>>>(dst_c2i, dst_i2c, cnt, cnt + NIMG);
  scanA_k<<<40, blk, 0, stream>>>(cnt, st_img, st_cls, bsum);
  scanC_k<<<40, blk, 0, stream>>>(bsum, st_img, st_cls);
  fill2_k<<<NE / 256, blk, 0, stream>>>(dst_c2i, src_c2i, st_img, cur, eix_c2i,
                                        dst_i2c, src_i2c, st_cls, cur + NIMG, eix_i2c);

  // ---- weight normalization (single launch) ----
  WNA wa;
  const float* wsrc[12] = { (const float*)d_in[4], (const float*)d_in[5],
                            (const float*)d_in[6], (const float*)d_in[7],
                            (const float*)d_in[8], (const float*)d_in[9],
                            (const float*)d_in[10], (const float*)d_in[11],
                            (const float*)d_in[12], (const float*)d_in[13],
                            (const float*)d_in[14], (const float*)d_in[15] };
  ushort* wdst[12] = { wn_in_img, wn_in_cls, wcat0, wcat0, wcat1, wcat1,
                       wcat2, wcat2, wcat3, wcat3, wn_out_img, wn_out_cls };
  const int wF[12]  = { 192, 128, 320, 256, 320, 256, 320, 256, 320, 256, 256, 256 };
  const int wOS[12] = { 192, 128, 576, 576, 576, 576, 576, 576, 576, 576, 256, 256 };
  const int wOO[12] = { 0, 0, 0, 320, 0, 320, 0, 320, 0, 320, 0, 0 };
  for (int i = 0; i < 12; ++i) {
    wa.w[i] = wsrc[i]; wa.o[i] = wdst[i]; wa.F[i] = wF[i]; wa.os[i] = wOS[i]; wa.oo[i] = wOO[i];
  }
  wnorm_all_k<<<dim3(256, 12), 64, 0, stream>>>(wa);

  // ---- input prep + projections ----
  cvt3_k<<<(2 * (size_t)NE * 64 + (size_t)NCLS * 128) / 1024, blk, 0, stream>>>(
      ea_c2i, ea_i2c, class_x, ea_c2i_bf, ea_i2c_bf, class_bf);
  xt_k<<<512, blk, 0, stream>>>(x, Xin);
  mgemm_k<<<dim3(NIMG / 128, 2), blk, 0, stream>>>(Xin, nullptr, wn_in_img,
                                                   H_img, 192, 256, 0, 0);
  mgemm_k<<<dim3(NCLS / 128, 2), blk, 0, stream>>>(class_bf, nullptr, wn_in_cls,
                                                   H_cls, 128, 256, 0, 0);

  // ---- layers ----
  const ushort* wc2i[2] = {wcat0, wcat2};
  const ushort* wi2c[2] = {wcat1, wcat3};
  for (int l = 0; l < 2; ++l) {
    silu2_k<<<((size_t)(NIMG + NCLS) * 256) / (8 * 256), blk, 0, stream>>>(
        H_img, H_cls, A_img, A_cls);
    agg2_k<<<(NIMG + NCLS) / 4, blk, 0, stream>>>(
        A_img, A_cls, ea_c2i_bf, ea_i2c_bf, eix_c2i, eix_i2c,
        st_img, st_cls, agg_img, agg_cls);
    mgemm_k<<<dim3(NIMG / 128, 2), blk, 0, stream>>>(A_img, agg_img, wc2i[l],
                                                     H_img, 576, 256, 2, 0);
    mgemm_k<<<dim3(NCLS / 128, 2), blk, 0, stream>>>(A_cls, agg_cls, wi2c[l],
                                                     H_cls, 576, 256, 2, 0);
    rownorm2_k<<<(NIMG + NCLS) / 4, blk, 0, stream>>>(H_img, H_cls);
  }

  // ---- output projections ----
  float* out_img = (float*)d_out;
  float* out_cls = (float*)d_out + (size_t)NIMG * 256;
  // img: swapped orientation (A=W 256xK, B=H) so NCHW store is coalesced
  mgemm_k<<<dim3(2, NIMG / 128), blk, 0, stream>>>(wn_out_img, nullptr, H_img,
                                                   out_img, 256, 0, 0, 1);
  mgemm_k<<<dim3(NCLS / 128, 2), blk, 0, stream>>>(H_cls, nullptr, wn_out_cls,
                                                   out_cls, 256, 256, 0, 2);
}

// Round 5
// 254.148 us; speedup vs baseline: 8.5539x; 1.2305x over previous
//
#include <hip/hip_runtime.h>
#include <cmath>

// ---- problem constants ----
constexpr int CIN  = 192;
constexpr int HW   = 4096;
constexpr int NIMG = 32768;
constexpr int NCLS = 8192;
constexpr int NE   = 131072;

#define EPSW 1e-4f
#define ALPHA 0.7905694150420949f    // mp_cat: Cc/sqrt(256)*0.5, Cc=sqrt(640)
#define BETA  1.5811388300841898f    // Cc/sqrt(64)*0.5
#define SILU_INV 1.6778523489932886f // 1/0.596

using bf16x8 = __attribute__((ext_vector_type(8))) __bf16;
using f32x4  = __attribute__((ext_vector_type(4))) float;

__device__ __forceinline__ ushort f2bf(float f) {   // RNE fp32->bf16
  uint u = __float_as_uint(f);
  u = (u + 0x7FFFu + ((u >> 16) & 1u)) >> 16;
  return (ushort)u;
}
__device__ __forceinline__ float bf2f(ushort h) {
  return __uint_as_float(((uint)h) << 16);
}
__device__ __forceinline__ float wave_red_sum(float v) {
  #pragma unroll
  for (int off = 32; off > 0; off >>= 1) v += __shfl_xor(v, off, 64);
  return v;
}
__device__ __forceinline__ int wave_red_sumi(int v) {
  #pragma unroll
  for (int off = 32; off > 0; off >>= 1) v += __shfl_xor(v, off, 64);
  return v;
}
__device__ __forceinline__ uint4 packbf8(float a0, float a1, float a2, float a3,
                                         float a4, float a5, float a6, float a7) {
  uint4 r;
  r.x = (uint)f2bf(a0) | ((uint)f2bf(a1) << 16);
  r.y = (uint)f2bf(a2) | ((uint)f2bf(a3) << 16);
  r.z = (uint)f2bf(a4) | ((uint)f2bf(a5) << 16);
  r.w = (uint)f2bf(a6) | ((uint)f2bf(a7) << 16);
  return r;
}

// ---- batched weight normalization -> bf16 ----
struct WNA {
  const float* w[12];
  ushort* o[12];
  int F[12];
  int os[12];
  int oo[12];
};
__global__ void wnorm_all_k(WNA a) {
  const int wi = blockIdx.y, row = blockIdx.x, lane = threadIdx.x;
  const int F = a.F[wi];
  const float* wr = a.w[wi] + (size_t)row * F;
  float ss = 0.f;
  for (int f = lane; f < F; f += 64) { float v = wr[f]; ss += v * v; }
  ss = wave_red_sum(ss);
  const float scale = 1.0f / (EPSW * sqrtf((float)F) + sqrtf(ss));
  ushort* o = a.o[wi] + (size_t)row * a.os[wi] + a.oo[wi];
  for (int f = lane; f < F; f += 64) o[f] = f2bf(wr[f] * scale);
}

// ---- CSR build ----
__global__ void counti_k(const int* __restrict__ d1, const int* __restrict__ d2,
                         int* __restrict__ c1, int* __restrict__ c2) {
  int e = blockIdx.x * 256 + threadIdx.x;
  atomicAdd(&c1[d1[e]], 1);
  atomicAdd(&c2[d2[e]], 1);
}

// blocks 0..31: img counts, 32..39: cls. Each block scans 1024 ints.
__global__ __launch_bounds__(256) void scanA_k(const int* __restrict__ cnt,
                                               int* __restrict__ st_img,
                                               int* __restrict__ st_cls,
                                               int* __restrict__ bsum) {
  const int bid = blockIdx.x;
  const bool cls = bid >= 32;
  const int* c = cnt + (cls ? NIMG : 0);
  int* s = cls ? st_cls : st_img;
  const int base = (cls ? bid - 32 : bid) * 1024;
  const int t = threadIdx.x, lane = t & 63, wid = t >> 6;
  int4 v = *(const int4*)(c + base + t * 4);
  const int i0 = v.x, i1 = i0 + v.y, i2 = i1 + v.z, i3 = i2 + v.w;
  int x = i3;
  #pragma unroll
  for (int off = 1; off < 64; off <<= 1) {
    int y = __shfl_up(x, off, 64);
    if (lane >= off) x += y;
  }
  const int pre = x - i3;
  __shared__ int wt[4];
  if (lane == 63) wt[wid] = x;
  __syncthreads();
  int woff = 0;
  #pragma unroll
  for (int i = 0; i < 4; ++i) if (i < wid) woff += wt[i];
  const int b = woff + pre;
  int4 o = { b, b + i0, b + i1, b + i2 };
  *(int4*)(s + base + t * 4) = o;
  if (t == 255) bsum[bid] = woff + x;
}

__global__ __launch_bounds__(256) void scanC_k(const int* __restrict__ bsum,
                                               int* __restrict__ st_img,
                                               int* __restrict__ st_cls) {
  const int bid = blockIdx.x;
  const bool cls = bid >= 32;
  const int seg0 = cls ? 32 : 0;
  const int t = threadIdx.x;
  __shared__ int off_s;
  if (t < 64) {
    int v = (t < bid - seg0) ? bsum[seg0 + t] : 0;
    v = wave_red_sumi(v);
    if (t == 0) off_s = v;
  }
  __syncthreads();
  const int off = off_s;
  int* s = cls ? st_cls : st_img;
  const int base = (cls ? bid - 32 : bid) * 1024;
  int4 v = *(int4*)(s + base + t * 4);
  v.x += off; v.y += off; v.z += off; v.w += off;
  *(int4*)(s + base + t * 4) = v;
  if (bid == 0 && t == 0) { st_img[NIMG] = NE; st_cls[NCLS] = NE; }
}

__global__ void fill2_k(const int* __restrict__ dst1, const int* __restrict__ src1,
                        const int* __restrict__ st1, int* __restrict__ cur1,
                        int2* __restrict__ eix1,
                        const int* __restrict__ dst2, const int* __restrict__ src2,
                        const int* __restrict__ st2, int* __restrict__ cur2,
                        int2* __restrict__ eix2) {
  int e = blockIdx.x * 256 + threadIdx.x;
  int d = dst1[e];
  int p = atomicAdd(&cur1[d], 1);
  eix1[st1[d] + p] = make_int2(e, src1[e]);
  d = dst2[e];
  p = atomicAdd(&cur2[d], 1);
  eix2[st2[d] + p] = make_int2(e, src2[e]);
}

// ---- per-dst EA mean (layer-invariant), fp32 gather -> bf16, BETA/deg folded ----
__global__ __launch_bounds__(256) void eam_k(
    const float* __restrict__ ea_ci, const float* __restrict__ ea_ic,
    const int2* __restrict__ eix_ci, const int2* __restrict__ eix_ic,
    const int* __restrict__ st_img, const int* __restrict__ st_cls,
    ushort* __restrict__ eam_img, ushort* __restrict__ eam_cls) {
  const int row  = blockIdx.x * 4 + (threadIdx.x >> 6);
  const int lane = threadIdx.x & 63;
  const float* EA; const int2* eix; const int* st; ushort* out; int r;
  if (row < NIMG) { r = row;        EA = ea_ci; eix = eix_ci; st = st_img;
                    out = eam_img + (size_t)r * 64; }
  else            { r = row - NIMG; EA = ea_ic; eix = eix_ic; st = st_cls;
                    out = eam_cls + (size_t)r * 64; }
  const int s0 = st[r], s1 = st[r + 1];
  float a = 0.f;
  for (int j = s0; j < s1; j += 4) {
    const int i1 = min(j + 1, s1 - 1), i2 = min(j + 2, s1 - 1), i3 = min(j + 3, s1 - 1);
    const int e0 = eix[j].x, e1 = eix[i1].x, e2 = eix[i2].x, e3 = eix[i3].x;
    const float w1 = (j + 1 < s1) ? 1.f : 0.f;
    const float w2 = (j + 2 < s1) ? 1.f : 0.f;
    const float w3 = (j + 3 < s1) ? 1.f : 0.f;
    float v0 = EA[(size_t)e0 * 64 + lane];
    float v1 = EA[(size_t)e1 * 64 + lane];
    float v2 = EA[(size_t)e2 * 64 + lane];
    float v3 = EA[(size_t)e3 * 64 + lane];
    a += v0 + w1 * v1 + w2 * v2 + w3 * v3;
  }
  const float c = BETA / fmaxf((float)(s1 - s0), 1.0f);
  out[lane] = f2bf(a * c);
}

// ---- CSR gather-mean of H only (img rows then cls rows), unroll-4, bf16 out ----
__global__ __launch_bounds__(256) void agg2_k(
    const ushort* __restrict__ Aimg, const ushort* __restrict__ Acls,
    const int2* __restrict__ eix_ci, const int2* __restrict__ eix_ic,
    const int* __restrict__ st_img, const int* __restrict__ st_cls,
    ushort* __restrict__ agg_img, ushort* __restrict__ agg_cls) {
  const int row  = blockIdx.x * 4 + (threadIdx.x >> 6);
  const int lane = threadIdx.x & 63;
  const ushort* Hs; const int2* eix; const int* st; ushort* out; int r;
  if (row < NIMG) { r = row;        Hs = Acls; eix = eix_ci; st = st_img;
                    out = agg_img + (size_t)r * 256; }
  else            { r = row - NIMG; Hs = Aimg; eix = eix_ic; st = st_cls;
                    out = agg_cls + (size_t)r * 256; }
  const int s0 = st[r], s1 = st[r + 1];
  float a0 = 0, a1 = 0, a2 = 0, a3 = 0;
  for (int j = s0; j < s1; j += 4) {
    const int i1 = min(j + 1, s1 - 1), i2 = min(j + 2, s1 - 1), i3 = min(j + 3, s1 - 1);
    const int sA = eix[j].y, sB = eix[i1].y, sC = eix[i2].y, sD = eix[i3].y;
    const float w1 = (j + 1 < s1) ? 1.f : 0.f;
    const float w2 = (j + 2 < s1) ? 1.f : 0.f;
    const float w3 = (j + 3 < s1) ? 1.f : 0.f;
    ushort4 h0 = *(const ushort4*)(Hs + (size_t)sA * 256 + lane * 4);
    ushort4 h1 = *(const ushort4*)(Hs + (size_t)sB * 256 + lane * 4);
    ushort4 h2 = *(const ushort4*)(Hs + (size_t)sC * 256 + lane * 4);
    ushort4 h3 = *(const ushort4*)(Hs + (size_t)sD * 256 + lane * 4);
    a0 += bf2f(h0.x) + w1 * bf2f(h1.x) + w2 * bf2f(h2.x) + w3 * bf2f(h3.x);
    a1 += bf2f(h0.y) + w1 * bf2f(h1.y) + w2 * bf2f(h2.y) + w3 * bf2f(h3.y);
    a2 += bf2f(h0.z) + w1 * bf2f(h1.z) + w2 * bf2f(h2.z) + w3 * bf2f(h3.z);
    a3 += bf2f(h0.w) + w1 * bf2f(h1.w) + w2 * bf2f(h2.w) + w3 * bf2f(h3.w);
  }
  const float c = ALPHA / fmaxf((float)(s1 - s0), 1.0f);
  ushort4 o = { f2bf(a0 * c), f2bf(a1 * c), f2bf(a2 * c), f2bf(a3 * c) };
  *(ushort4*)(out + lane * 4) = o;
}

// ---- fused bf16 MFMA GEMM: 512 threads, tile 128 rows x 256 cols, BK=32 ----
// A-source modes:
//   1: x NCHW fp32 (row = b*4096+hw, k = channel)
//   2: concat k<256 agg bf16 [M,256]; 256..319 eam bf16 [M,64]; >=320 AD bf16 [M,256]
//   3: fp32 row-major [M,K]
// Epilogue: optional row-L2-norm (cross-wave LDS reduce), optional silu; bf16 out [M,256].
__device__ __forceinline__ int lds_swz(int row, int kbyte) {
  return ((row << 6) + kbyte) ^ ((row & 7) << 4);
}

__global__ __launch_bounds__(512) void fgemm_k(
    const ushort* __restrict__ AD, const ushort* __restrict__ AG,
    const ushort* __restrict__ EAM, const float* __restrict__ AF,
    const ushort* __restrict__ B, ushort* __restrict__ O,
    int K, int a_mode, int do_norm, int do_silu) {
  __shared__ char ldsb[24576];
  ushort* As = (ushort*)ldsb;            // 128 x 32 bf16 (8 KB)
  ushort* Bs = (ushort*)(ldsb + 8192);   // 256 x 32 bf16 (16 KB)
  const int t    = threadIdx.x;
  const int row0 = blockIdx.x * 128;
  const int srowA = t >> 2, skA = (t & 3) * 8;   // A: 1 x uint4 per thread
  const int srowB = t >> 1, skB = (t & 1) * 16;  // B: 2 x uint4 per thread
  const int wid = t >> 6, lane = t & 63;
  const int wr = (wid >> 2) * 64, wcq = wid & 3, wc = wcq * 64;
  const int l15 = lane & 15, q = lane >> 4, lk16 = q * 16;
  f32x4 acc[4][4] = {};

  uint4 areg, breg0, breg1;
  auto loadA = [&](int k0) {
    const int row = row0 + srowA;
    if (a_mode == 2) {
      const int kk = k0 + skA;
      const ushort* p = (kk < 256) ? AG + (size_t)row * 256 + kk
                      : (kk < 320) ? EAM + (size_t)row * 64 + (kk - 256)
                                   : AD + (size_t)row * 256 + (kk - 320);
      areg = *(const uint4*)p;
    } else if (a_mode == 3) {
      const float* p = AF + (size_t)row * K + k0 + skA;
      float4 f0 = *(const float4*)p;
      float4 f1 = *(const float4*)(p + 4);
      areg = packbf8(f0.x, f0.y, f0.z, f0.w, f1.x, f1.y, f1.z, f1.w);
    } else { // a_mode 1: x NCHW fp32
      const int b = row >> 12, hw = row & 4095;
      const float* p = AF + ((size_t)(b * CIN + k0 + skA)) * HW + hw;
      float f0 = p[0], f1 = p[HW], f2 = p[2 * HW], f3 = p[3 * HW];
      float f4 = p[4 * HW], f5 = p[5 * HW], f6 = p[6 * HW], f7 = p[7 * HW];
      areg = packbf8(f0, f1, f2, f3, f4, f5, f6, f7);
    }
  };
  auto loadB = [&](int k0) {
    const ushort* p = B + (size_t)srowB * K + k0 + skB;
    breg0 = *(const uint4*)p;
    breg1 = *(const uint4*)(p + 8);
  };

  loadA(0); loadB(0);
  for (int k0 = 0; k0 < K; k0 += 32) {
    __syncthreads();
    *(uint4*)((char*)As + lds_swz(srowA, skA * 2)) = areg;
    *(uint4*)((char*)Bs + lds_swz(srowB, skB * 2)) = breg0;
    *(uint4*)((char*)Bs + lds_swz(srowB, skB * 2 + 16)) = breg1;
    __syncthreads();
    if (k0 + 32 < K) { loadA(k0 + 32); loadB(k0 + 32); }
    bf16x8 af[4], bfr[4];
    #pragma unroll
    for (int m = 0; m < 4; ++m)
      af[m] = *(const bf16x8*)((const char*)As + lds_swz(wr + m * 16 + l15, lk16));
    #pragma unroll
    for (int n = 0; n < 4; ++n)
      bfr[n] = *(const bf16x8*)((const char*)Bs + lds_swz(wc + n * 16 + l15, lk16));
    #pragma unroll
    for (int m = 0; m < 4; ++m)
      #pragma unroll
      for (int n = 0; n < 4; ++n)
        acc[m][n] = __builtin_amdgcn_mfma_f32_16x16x32_bf16(af[m], bfr[n], acc[m][n], 0, 0, 0);
  }

  // ---- epilogue: optional row-L2 norm across the 4 col-waves, optional silu ----
  float sc_row[4][4];
  #pragma unroll
  for (int m = 0; m < 4; ++m)
    #pragma unroll
    for (int j = 0; j < 4; ++j) sc_row[m][j] = 1.0f;
  if (do_norm) {
    __syncthreads();
    float* part = (float*)ldsb;   // [128][4]
    #pragma unroll
    for (int m = 0; m < 4; ++m)
      #pragma unroll
      for (int j = 0; j < 4; ++j) {
        float ss = 0.f;
        #pragma unroll
        for (int n = 0; n < 4; ++n) { float v = acc[m][n][j]; ss += v * v; }
        ss += __shfl_xor(ss, 1, 64); ss += __shfl_xor(ss, 2, 64);
        ss += __shfl_xor(ss, 4, 64); ss += __shfl_xor(ss, 8, 64);
        if (l15 == 0) part[(wr + m * 16 + q * 4 + j) * 4 + wcq] = ss;
      }
    __syncthreads();
    #pragma unroll
    for (int m = 0; m < 4; ++m)
      #pragma unroll
      for (int j = 0; j < 4; ++j) {
        float4 p4 = *(float4*)&part[(wr + m * 16 + q * 4 + j) * 4];
        sc_row[m][j] = 1.0f / fmaxf(sqrtf(p4.x + p4.y + p4.z + p4.w), 1e-12f);
      }
  }
  #pragma unroll
  for (int m = 0; m < 4; ++m)
    #pragma unroll
    for (int j = 0; j < 4; ++j) {
      const int r = row0 + wr + m * 16 + q * 4 + j;
      #pragma unroll
      for (int n = 0; n < 4; ++n) {
        float v = acc[m][n][j] * sc_row[m][j];
        if (do_silu) v = (v / (1.0f + __expf(-v))) * SILU_INV;
        O[(size_t)r * 256 + wc + n * 16 + l15] = f2bf(v);
      }
    }
}

// ---- plain bf16 MFMA GEMM for outputs: 256 threads, tile 128x128 ----
// c_mode 1: fp32 img NCHW C[((col>>12)*256+row)*4096+(col&4095)]; 2: fp32 [M,ldc]
__global__ __launch_bounds__(256) void mgemm_k(
    const ushort* __restrict__ A, const ushort* __restrict__ B,
    float* __restrict__ C, int K, int ldc, int c_mode) {
  __shared__ ushort As[128 * 32];
  __shared__ ushort Bs[128 * 32];
  const int t    = threadIdx.x;
  const int row0 = blockIdx.x * 128, col0 = blockIdx.y * 128;
  const int srow = t >> 1;
  const int skh  = (t & 1) * 16;
  const int w    = t >> 6, lane = t & 63;
  const int wr   = (w >> 1) * 64, wc = (w & 1) * 64;
  const int l15  = lane & 15, lk16 = (lane >> 4) * 16;
  f32x4 acc[4][4] = {};

  uint4 ar0, ar1, br0, br1;
  auto loadA = [&](int k0) {
    const ushort* p = A + (size_t)(row0 + srow) * K + k0 + skh;
    ar0 = *(const uint4*)(p);
    ar1 = *(const uint4*)(p + 8);
  };
  auto loadB = [&](int k0) {
    const ushort* p = B + (size_t)(col0 + srow) * K + k0 + skh;
    br0 = *(const uint4*)(p);
    br1 = *(const uint4*)(p + 8);
  };

  loadA(0); loadB(0);
  for (int k0 = 0; k0 < K; k0 += 32) {
    __syncthreads();
    *(uint4*)((char*)As + lds_swz(srow, skh * 2))      = ar0;
    *(uint4*)((char*)As + lds_swz(srow, skh * 2 + 16)) = ar1;
    *(uint4*)((char*)Bs + lds_swz(srow, skh * 2))      = br0;
    *(uint4*)((char*)Bs + lds_swz(srow, skh * 2 + 16)) = br1;
    __syncthreads();
    if (k0 + 32 < K) { loadA(k0 + 32); loadB(k0 + 32); }
    bf16x8 af[4], bfr[4];
    #pragma unroll
    for (int m = 0; m < 4; ++m)
      af[m] = *(const bf16x8*)((const char*)As + lds_swz(wr + m * 16 + l15, lk16));
    #pragma unroll
    for (int n = 0; n < 4; ++n)
      bfr[n] = *(const bf16x8*)((const char*)Bs + lds_swz(wc + n * 16 + l15, lk16));
    #pragma unroll
    for (int m = 0; m < 4; ++m)
      #pragma unroll
      for (int n = 0; n < 4; ++n)
        acc[m][n] = __builtin_amdgcn_mfma_f32_16x16x32_bf16(af[m], bfr[n], acc[m][n], 0, 0, 0);
  }

  #pragma unroll
  for (int m = 0; m < 4; ++m) {
    const int rbase = row0 + wr + m * 16 + (lane >> 4) * 4;
    #pragma unroll
    for (int n = 0; n < 4; ++n) {
      const int col = col0 + wc + n * 16 + l15;
      #pragma unroll
      for (int j = 0; j < 4; ++j) {
        const int r = rbase + j;
        if (c_mode == 1)
          C[((size_t)(col >> 12) * 256 + r) * 4096 + (col & 4095)] = acc[m][n][j];
        else
          C[(size_t)r * ldc + col] = acc[m][n][j];
      }
    }
  }
}

extern "C" void kernel_launch(void* const* d_in, const int* in_sizes, int n_in,
                              void* d_out, int out_size, void* d_ws, size_t ws_size,
                              hipStream_t stream) {
  const float* x        = (const float*)d_in[0];
  const float* class_x  = (const float*)d_in[1];
  const float* ea_c2i   = (const float*)d_in[2];
  const float* ea_i2c   = (const float*)d_in[3];
  const int* src_c2i = (const int*)d_in[16];
  const int* dst_c2i = (const int*)d_in[17];
  const int* src_i2c = (const int*)d_in[18];
  const int* dst_i2c = (const int*)d_in[19];

  float* ws = (float*)d_ws;
  size_t off = 0;
  auto alloc = [&](size_t n) { float* p = ws + off; off += (n + 15) & ~(size_t)15; return p; };

  ushort* A_img   = (ushort*)alloc((size_t)NIMG * 128);   // bf16 [NIMG,256] activations
  ushort* A_cls   = (ushort*)alloc((size_t)NCLS * 128);
  ushort* H_img   = (ushort*)alloc((size_t)NIMG * 128);   // layer-2 normed outputs
  ushort* H_cls   = (ushort*)alloc((size_t)NCLS * 128);
  ushort* agg_img = (ushort*)alloc((size_t)NIMG * 128);   // bf16 [NIMG,256] H-mean
  ushort* agg_cls = (ushort*)alloc((size_t)NCLS * 128);
  ushort* eam_img = (ushort*)alloc((size_t)NIMG * 32);    // bf16 [NIMG,64] EA-mean
  ushort* eam_cls = (ushort*)alloc((size_t)NCLS * 32);
  int* cnt       = (int*)alloc(2 * (NIMG + NCLS));        // cnt | cur (one memset)
  int* cur       = cnt + (NIMG + NCLS);
  int* bsum      = (int*)alloc(48);
  int* st_img    = (int*)alloc(NIMG + 1 + NCLS + 1 + 14);
  int* st_cls    = st_img + NIMG + 1;
  int2* eix_c2i  = (int2*)alloc((size_t)NE * 2);          // {edge, src}
  int2* eix_i2c  = (int2*)alloc((size_t)NE * 2);
  ushort* wn_in_img  = (ushort*)alloc(256 * 96);
  ushort* wn_in_cls  = (ushort*)alloc(256 * 64);
  ushort* wcat0      = (ushort*)alloc(256 * 288);
  ushort* wcat1      = (ushort*)alloc(256 * 288);
  ushort* wcat2      = (ushort*)alloc(256 * 288);
  ushort* wcat3      = (ushort*)alloc(256 * 288);
  ushort* wn_out_img = (ushort*)alloc(256 * 128);
  ushort* wn_out_cls = (ushort*)alloc(256 * 128);

  const dim3 blk(256);

  // ---- CSR build ----
  hipMemsetAsync(cnt, 0, (size_t)2 * (NIMG + NCLS) * sizeof(int), stream);
  counti_k<<<NE / 256, blk, 0, stream>>>(dst_c2i, dst_i2c, cnt, cnt + NIMG);
  scanA_k<<<40, blk, 0, stream>>>(cnt, st_img, st_cls, bsum);
  scanC_k<<<40, blk, 0, stream>>>(bsum, st_img, st_cls);
  fill2_k<<<NE / 256, blk, 0, stream>>>(dst_c2i, src_c2i, st_img, cur, eix_c2i,
                                        dst_i2c, src_i2c, st_cls, cur + NIMG, eix_i2c);
  // EA mean per dst (layer-invariant)
  eam_k<<<(NIMG + NCLS) / 4, blk, 0, stream>>>(ea_c2i, ea_i2c, eix_c2i, eix_i2c,
                                               st_img, st_cls, eam_img, eam_cls);

  // ---- weight normalization (single launch) ----
  WNA wa;
  const float* wsrc[12] = { (const float*)d_in[4], (const float*)d_in[5],
                            (const float*)d_in[6], (const float*)d_in[7],
                            (const float*)d_in[8], (const float*)d_in[9],
                            (const float*)d_in[10], (const float*)d_in[11],
                            (const float*)d_in[12], (const float*)d_in[13],
                            (const float*)d_in[14], (const float*)d_in[15] };
  ushort* wdst[12] = { wn_in_img, wn_in_cls, wcat0, wcat0, wcat1, wcat1,
                       wcat2, wcat2, wcat3, wcat3, wn_out_img, wn_out_cls };
  const int wF[12]  = { 192, 128, 320, 256, 320, 256, 320, 256, 320, 256, 256, 256 };
  const int wOS[12] = { 192, 128, 576, 576, 576, 576, 576, 576, 576, 576, 256, 256 };
  const int wOO[12] = { 0, 0, 0, 320, 0, 320, 0, 320, 0, 320, 0, 0 };
  for (int i = 0; i < 12; ++i) {
    wa.w[i] = wsrc[i]; wa.o[i] = wdst[i]; wa.F[i] = wF[i]; wa.os[i] = wOS[i]; wa.oo[i] = wOO[i];
  }
  wnorm_all_k<<<dim3(256, 12), 64, 0, stream>>>(wa);

  // ---- input projections (read fp32 sources directly, emit silu'd A) ----
  fgemm_k<<<NIMG / 128, 512, 0, stream>>>(nullptr, nullptr, nullptr, x,
                                          wn_in_img, A_img, 192, 1, 0, 1);
  fgemm_k<<<NCLS / 128, 512, 0, stream>>>(nullptr, nullptr, nullptr, class_x,
                                          wn_in_cls, A_cls, 128, 3, 0, 1);

  // ---- layer 1: conv -> norm -> silu (A in-place) ----
  agg2_k<<<(NIMG + NCLS) / 4, blk, 0, stream>>>(A_img, A_cls, eix_c2i, eix_i2c,
                                                st_img, st_cls, agg_img, agg_cls);
  fgemm_k<<<NIMG / 128, 512, 0, stream>>>(A_img, agg_img, eam_img, nullptr,
                                          wcat0, A_img, 576, 2, 1, 1);
  fgemm_k<<<NCLS / 128, 512, 0, stream>>>(A_cls, agg_cls, eam_cls, nullptr,
                                          wcat1, A_cls, 576, 2, 1, 1);

  // ---- layer 2: conv -> norm (H out) ----
  agg2_k<<<(NIMG + NCLS) / 4, blk, 0, stream>>>(A_img, A_cls, eix_c2i, eix_i2c,
                                                st_img, st_cls, agg_img, agg_cls);
  fgemm_k<<<NIMG / 128, 512, 0, stream>>>(A_img, agg_img, eam_img, nullptr,
                                          wcat2, H_img, 576, 2, 1, 0);
  fgemm_k<<<NCLS / 128, 512, 0, stream>>>(A_cls, agg_cls, eam_cls, nullptr,
                                          wcat3, H_cls, 576, 2, 1, 0);

  // ---- output projections ----
  float* out_img = (float*)d_out;
  float* out_cls = (float*)d_out + (size_t)NIMG * 256;
  // img: swapped orientation (A=W 256xK, B=H) so NCHW store is coalesced
  mgemm_k<<<dim3(2, NIMG / 128), blk, 0, stream>>>(wn_out_img, H_img,
                                                   out_img, 256, 0, 1);
  mgemm_k<<<dim3(NCLS / 128, 2), blk, 0, stream>>>(H_cls, wn_out_cls,
                                                   out_cls, 256, 256, 2);
}

// Round 6
// 226.977 us; speedup vs baseline: 9.5779x; 1.1197x over previous
//
#include <hip/hip_runtime.h>
#include <cmath>

// ---- problem constants ----
constexpr int CIN  = 192;
constexpr int HW   = 4096;
constexpr int NIMG = 32768;
constexpr int NCLS = 8192;
constexpr int NE   = 131072;

#define EPSW 1e-4f
#define ALPHA 0.7905694150420949f    // mp_cat: Cc/sqrt(256)*0.5, Cc=sqrt(640)
#define BETA  1.5811388300841898f    // Cc/sqrt(64)*0.5
#define SILU_INV 1.6778523489932886f // 1/0.596

using bf16x8 = __attribute__((ext_vector_type(8))) __bf16;
using f32x4  = __attribute__((ext_vector_type(4))) float;

__device__ __forceinline__ ushort f2bf(float f) {   // RNE fp32->bf16
  uint u = __float_as_uint(f);
  u = (u + 0x7FFFu + ((u >> 16) & 1u)) >> 16;
  return (ushort)u;
}
__device__ __forceinline__ float bf2f(ushort h) {
  return __uint_as_float(((uint)h) << 16);
}
__device__ __forceinline__ float wave_red_sum(float v) {
  #pragma unroll
  for (int off = 32; off > 0; off >>= 1) v += __shfl_xor(v, off, 64);
  return v;
}
__device__ __forceinline__ int wave_red_sumi(int v) {
  #pragma unroll
  for (int off = 32; off > 0; off >>= 1) v += __shfl_xor(v, off, 64);
  return v;
}
__device__ __forceinline__ uint4 packbf8(float a0, float a1, float a2, float a3,
                                         float a4, float a5, float a6, float a7) {
  uint4 r;
  r.x = (uint)f2bf(a0) | ((uint)f2bf(a1) << 16);
  r.y = (uint)f2bf(a2) | ((uint)f2bf(a3) << 16);
  r.z = (uint)f2bf(a4) | ((uint)f2bf(a5) << 16);
  r.w = (uint)f2bf(a6) | ((uint)f2bf(a7) << 16);
  return r;
}

// ---- fused prologue: weight-norm (12 matrices, wave per row) + edge counts ----
struct WNA {
  const float* w[12];
  ushort* o[12];
  int F[12];
  int os[12];
  int oo[12];
};
__global__ __launch_bounds__(256) void pre_k(WNA a,
                                             const int* __restrict__ d1,
                                             const int* __restrict__ d2,
                                             int* __restrict__ c1,
                                             int* __restrict__ c2) {
  const int bx = blockIdx.x, t = threadIdx.x;
  if (bx < 768) {           // wnorm: 64 blocks/matrix, 4 rows/block (wave per row)
    const int wi = bx >> 6;
    const int row = ((bx & 63) << 2) + (t >> 6);
    const int lane = t & 63;
    const int F = a.F[wi];
    const float* wr = a.w[wi] + (size_t)row * F;
    float ss = 0.f;
    for (int f = lane; f < F; f += 64) { float v = wr[f]; ss += v * v; }
    ss = wave_red_sum(ss);
    const float scale = 1.0f / (EPSW * sqrtf((float)F) + sqrtf(ss));
    ushort* o = a.o[wi] + (size_t)row * a.os[wi] + a.oo[wi];
    for (int f = lane; f < F; f += 64) o[f] = f2bf(wr[f] * scale);
  } else {                  // counti: 512 blocks
    const int e = (bx - 768) * 256 + t;
    atomicAdd(&c1[d1[e]], 1);
    atomicAdd(&c2[d2[e]], 1);
  }
}

// blocks 0..31: img counts, 32..39: cls. Each block scans 1024 ints.
__global__ __launch_bounds__(256) void scanA_k(const int* __restrict__ cnt,
                                               int* __restrict__ st_img,
                                               int* __restrict__ st_cls,
                                               int* __restrict__ bsum) {
  const int bid = blockIdx.x;
  const bool cls = bid >= 32;
  const int* c = cnt + (cls ? NIMG : 0);
  int* s = cls ? st_cls : st_img;
  const int base = (cls ? bid - 32 : bid) * 1024;
  const int t = threadIdx.x, lane = t & 63, wid = t >> 6;
  int4 v = *(const int4*)(c + base + t * 4);
  const int i0 = v.x, i1 = i0 + v.y, i2 = i1 + v.z, i3 = i2 + v.w;
  int x = i3;
  #pragma unroll
  for (int off = 1; off < 64; off <<= 1) {
    int y = __shfl_up(x, off, 64);
    if (lane >= off) x += y;
  }
  const int pre = x - i3;
  __shared__ int wt[4];
  if (lane == 63) wt[wid] = x;
  __syncthreads();
  int woff = 0;
  #pragma unroll
  for (int i = 0; i < 4; ++i) if (i < wid) woff += wt[i];
  const int b = woff + pre;
  int4 o = { b, b + i0, b + i1, b + i2 };
  *(int4*)(s + base + t * 4) = o;
  if (t == 255) bsum[bid] = woff + x;
}

__global__ __launch_bounds__(256) void scanC_k(const int* __restrict__ bsum,
                                               int* __restrict__ st_img,
                                               int* __restrict__ st_cls) {
  const int bid = blockIdx.x;
  const bool cls = bid >= 32;
  const int seg0 = cls ? 32 : 0;
  const int t = threadIdx.x;
  __shared__ int off_s;
  if (t < 64) {
    int v = (t < bid - seg0) ? bsum[seg0 + t] : 0;
    v = wave_red_sumi(v);
    if (t == 0) off_s = v;
  }
  __syncthreads();
  const int off = off_s;
  int* s = cls ? st_cls : st_img;
  const int base = (cls ? bid - 32 : bid) * 1024;
  int4 v = *(int4*)(s + base + t * 4);
  v.x += off; v.y += off; v.z += off; v.w += off;
  *(int4*)(s + base + t * 4) = v;
  if (bid == 0 && t == 0) { st_img[NIMG] = NE; st_cls[NCLS] = NE; }
}

__global__ void fill2_k(const int* __restrict__ dst1, const int* __restrict__ src1,
                        const int* __restrict__ st1, int* __restrict__ cur1,
                        int2* __restrict__ eix1,
                        const int* __restrict__ dst2, const int* __restrict__ src2,
                        const int* __restrict__ st2, int* __restrict__ cur2,
                        int2* __restrict__ eix2) {
  int e = blockIdx.x * 256 + threadIdx.x;
  int d = dst1[e];
  int p = atomicAdd(&cur1[d], 1);
  eix1[st1[d] + p] = make_int2(e, src1[e]);
  d = dst2[e];
  p = atomicAdd(&cur2[d], 1);
  eix2[st2[d] + p] = make_int2(e, src2[e]);
}

// ---- CSR gather-mean of H (img rows then cls rows), unroll-4, bf16 out ----
// do_eam: additionally compute per-dst EA mean (fp32 gather, BETA/deg folded).
__global__ __launch_bounds__(256) void agg2_k(
    const ushort* __restrict__ Aimg, const ushort* __restrict__ Acls,
    const int2* __restrict__ eix_ci, const int2* __restrict__ eix_ic,
    const int* __restrict__ st_img, const int* __restrict__ st_cls,
    ushort* __restrict__ agg_img, ushort* __restrict__ agg_cls,
    const float* __restrict__ ea_ci, const float* __restrict__ ea_ic,
    ushort* __restrict__ eam_img, ushort* __restrict__ eam_cls, int do_eam) {
  const int row  = blockIdx.x * 4 + (threadIdx.x >> 6);
  const int lane = threadIdx.x & 63;
  const ushort* Hs; const int2* eix; const int* st; ushort* out;
  const float* EA; ushort* oute; int r;
  if (row < NIMG) { r = row;        Hs = Acls; eix = eix_ci; st = st_img;
                    out = agg_img + (size_t)r * 256; EA = ea_ci;
                    oute = eam_img + (size_t)r * 64; }
  else            { r = row - NIMG; Hs = Aimg; eix = eix_ic; st = st_cls;
                    out = agg_cls + (size_t)r * 256; EA = ea_ic;
                    oute = eam_cls + (size_t)r * 64; }
  const int s0 = st[r], s1 = st[r + 1];
  float a0 = 0, a1 = 0, a2 = 0, a3 = 0, ae = 0;
  for (int j = s0; j < s1; j += 4) {
    const int i1 = min(j + 1, s1 - 1), i2 = min(j + 2, s1 - 1), i3 = min(j + 3, s1 - 1);
    const int2 e0 = eix[j], e1 = eix[i1], e2 = eix[i2], e3 = eix[i3];
    const float w1 = (j + 1 < s1) ? 1.f : 0.f;
    const float w2 = (j + 2 < s1) ? 1.f : 0.f;
    const float w3 = (j + 3 < s1) ? 1.f : 0.f;
    ushort4 h0 = *(const ushort4*)(Hs + (size_t)e0.y * 256 + lane * 4);
    ushort4 h1 = *(const ushort4*)(Hs + (size_t)e1.y * 256 + lane * 4);
    ushort4 h2 = *(const ushort4*)(Hs + (size_t)e2.y * 256 + lane * 4);
    ushort4 h3 = *(const ushort4*)(Hs + (size_t)e3.y * 256 + lane * 4);
    a0 += bf2f(h0.x) + w1 * bf2f(h1.x) + w2 * bf2f(h2.x) + w3 * bf2f(h3.x);
    a1 += bf2f(h0.y) + w1 * bf2f(h1.y) + w2 * bf2f(h2.y) + w3 * bf2f(h3.y);
    a2 += bf2f(h0.z) + w1 * bf2f(h1.z) + w2 * bf2f(h2.z) + w3 * bf2f(h3.z);
    a3 += bf2f(h0.w) + w1 * bf2f(h1.w) + w2 * bf2f(h2.w) + w3 * bf2f(h3.w);
    if (do_eam) {
      ae += EA[(size_t)e0.x * 64 + lane] + w1 * EA[(size_t)e1.x * 64 + lane]
          + w2 * EA[(size_t)e2.x * 64 + lane] + w3 * EA[(size_t)e3.x * 64 + lane];
    }
  }
  const float inv = 1.0f / fmaxf((float)(s1 - s0), 1.0f);
  const float c = ALPHA * inv;
  ushort4 o = { f2bf(a0 * c), f2bf(a1 * c), f2bf(a2 * c), f2bf(a3 * c) };
  *(ushort4*)(out + lane * 4) = o;
  if (do_eam) oute[lane] = f2bf(ae * BETA * inv);
}

// ---- fused bf16 MFMA GEMM body: 512 threads, tile 128 rows x 256 cols, BK=32 ----
// a_mode 1: x NCHW fp32; 2: concat agg|eam|AD bf16; 3: fp32 row-major [M,K]
__device__ __forceinline__ int lds_swz(int row, int kbyte) {
  return ((row << 6) + kbyte) ^ ((row & 7) << 4);
}

struct FJ {
  const ushort* AD; const ushort* AG; const ushort* EAM;
  const float* AF; const ushort* B; ushort* O;
  int K, a_mode, do_norm, do_silu;
};

__device__ __forceinline__ void fgemm_body(const FJ J, int bx, char* ldsb) {
  ushort* As = (ushort*)ldsb;            // 128 x 32 bf16 (8 KB)
  ushort* Bs = (ushort*)(ldsb + 8192);   // 256 x 32 bf16 (16 KB)
  const int t    = threadIdx.x;
  const int row0 = bx * 128;
  const int srowA = t >> 2, skA = (t & 3) * 8;
  const int srowB = t >> 1, skB = (t & 1) * 16;
  const int wid = t >> 6, lane = t & 63;
  const int wr = (wid >> 2) * 64, wcq = wid & 3, wc = wcq * 64;
  const int l15 = lane & 15, q = lane >> 4, lk16 = q * 16;
  const int K = J.K;
  f32x4 acc[4][4] = {};

  uint4 areg, breg0, breg1;
  auto loadA = [&](int k0) {
    const int row = row0 + srowA;
    if (J.a_mode == 2) {
      const int kk = k0 + skA;
      const ushort* p = (kk < 256) ? J.AG + (size_t)row * 256 + kk
                      : (kk < 320) ? J.EAM + (size_t)row * 64 + (kk - 256)
                                   : J.AD + (size_t)row * 256 + (kk - 320);
      areg = *(const uint4*)p;
    } else if (J.a_mode == 3) {
      const float* p = J.AF + (size_t)row * K + k0 + skA;
      float4 f0 = *(const float4*)p;
      float4 f1 = *(const float4*)(p + 4);
      areg = packbf8(f0.x, f0.y, f0.z, f0.w, f1.x, f1.y, f1.z, f1.w);
    } else { // a_mode 1: x NCHW fp32
      const int b = row >> 12, hw = row & 4095;
      const float* p = J.AF + ((size_t)(b * CIN + k0 + skA)) * HW + hw;
      float f0 = p[0], f1 = p[HW], f2 = p[2 * HW], f3 = p[3 * HW];
      float f4 = p[4 * HW], f5 = p[5 * HW], f6 = p[6 * HW], f7 = p[7 * HW];
      areg = packbf8(f0, f1, f2, f3, f4, f5, f6, f7);
    }
  };
  auto loadB = [&](int k0) {
    const ushort* p = J.B + (size_t)srowB * K + k0 + skB;
    breg0 = *(const uint4*)p;
    breg1 = *(const uint4*)(p + 8);
  };

  loadA(0); loadB(0);
  for (int k0 = 0; k0 < K; k0 += 32) {
    __syncthreads();
    *(uint4*)(ldsb + lds_swz(srowA, skA * 2)) = areg;
    *(uint4*)((char*)Bs + lds_swz(srowB, skB * 2)) = breg0;
    *(uint4*)((char*)Bs + lds_swz(srowB, skB * 2 + 16)) = breg1;
    __syncthreads();
    if (k0 + 32 < K) { loadA(k0 + 32); loadB(k0 + 32); }
    bf16x8 af[4], bfr[4];
    #pragma unroll
    for (int m = 0; m < 4; ++m)
      af[m] = *(const bf16x8*)((const char*)As + lds_swz(wr + m * 16 + l15, lk16));
    #pragma unroll
    for (int n = 0; n < 4; ++n)
      bfr[n] = *(const bf16x8*)((const char*)Bs + lds_swz(wc + n * 16 + l15, lk16));
    #pragma unroll
    for (int m = 0; m < 4; ++m)
      #pragma unroll
      for (int n = 0; n < 4; ++n)
        acc[m][n] = __builtin_amdgcn_mfma_f32_16x16x32_bf16(af[m], bfr[n], acc[m][n], 0, 0, 0);
  }

  float sc_row[4][4];
  #pragma unroll
  for (int m = 0; m < 4; ++m)
    #pragma unroll
    for (int j = 0; j < 4; ++j) sc_row[m][j] = 1.0f;
  if (J.do_norm) {
    __syncthreads();
    float* part = (float*)ldsb;   // [128][4]
    #pragma unroll
    for (int m = 0; m < 4; ++m)
      #pragma unroll
      for (int j = 0; j < 4; ++j) {
        float ss = 0.f;
        #pragma unroll
        for (int n = 0; n < 4; ++n) { float v = acc[m][n][j]; ss += v * v; }
        ss += __shfl_xor(ss, 1, 64); ss += __shfl_xor(ss, 2, 64);
        ss += __shfl_xor(ss, 4, 64); ss += __shfl_xor(ss, 8, 64);
        if (l15 == 0) part[(wr + m * 16 + q * 4 + j) * 4 + wcq] = ss;
      }
    __syncthreads();
    #pragma unroll
    for (int m = 0; m < 4; ++m)
      #pragma unroll
      for (int j = 0; j < 4; ++j) {
        float4 p4 = *(float4*)&part[(wr + m * 16 + q * 4 + j) * 4];
        sc_row[m][j] = 1.0f / fmaxf(sqrtf(p4.x + p4.y + p4.z + p4.w), 1e-12f);
      }
  }
  #pragma unroll
  for (int m = 0; m < 4; ++m)
    #pragma unroll
    for (int j = 0; j < 4; ++j) {
      const int r = row0 + wr + m * 16 + q * 4 + j;
      #pragma unroll
      for (int n = 0; n < 4; ++n) {
        float v = acc[m][n][j] * sc_row[m][j];
        if (J.do_silu) v = (v / (1.0f + __expf(-v))) * SILU_INV;
        J.O[(size_t)r * 256 + wc + n * 16 + l15] = f2bf(v);
      }
    }
}

__global__ __launch_bounds__(512) void fgemm2_k(FJ j0, FJ j1, int n0) {
  __shared__ char ldsb[24576];
  const int bx = blockIdx.x;
  if (bx < n0) fgemm_body(j0, bx, ldsb);
  else         fgemm_body(j1, bx - n0, ldsb);
}

// ---- plain bf16 MFMA GEMM body for outputs: 256 threads, tile 128x128 ----
// c_mode 1: fp32 img NCHW C[((col>>12)*256+row)*4096+(col&4095)]; 2: fp32 [M,ldc]
__device__ __forceinline__ void mgemm_body(
    const ushort* __restrict__ A, const ushort* __restrict__ B,
    float* __restrict__ C, int K, int ldc, int c_mode,
    int row0, int col0, char* ldsb) {
  ushort* As = (ushort*)ldsb;
  ushort* Bs = (ushort*)(ldsb + 8192);
  const int t    = threadIdx.x;
  const int srow = t >> 1;
  const int skh  = (t & 1) * 16;
  const int w    = t >> 6, lane = t & 63;
  const int wr   = (w >> 1) * 64, wc = (w & 1) * 64;
  const int l15  = lane & 15, lk16 = (lane >> 4) * 16;
  f32x4 acc[4][4] = {};

  uint4 ar0, ar1, br0, br1;
  auto loadA = [&](int k0) {
    const ushort* p = A + (size_t)(row0 + srow) * K + k0 + skh;
    ar0 = *(const uint4*)(p);
    ar1 = *(const uint4*)(p + 8);
  };
  auto loadB = [&](int k0) {
    const ushort* p = B + (size_t)(col0 + srow) * K + k0 + skh;
    br0 = *(const uint4*)(p);
    br1 = *(const uint4*)(p + 8);
  };

  loadA(0); loadB(0);
  for (int k0 = 0; k0 < K; k0 += 32) {
    __syncthreads();
    *(uint4*)((char*)As + lds_swz(srow, skh * 2))      = ar0;
    *(uint4*)((char*)As + lds_swz(srow, skh * 2 + 16)) = ar1;
    *(uint4*)((char*)Bs + lds_swz(srow, skh * 2))      = br0;
    *(uint4*)((char*)Bs + lds_swz(srow, skh * 2 + 16)) = br1;
    __syncthreads();
    if (k0 + 32 < K) { loadA(k0 + 32); loadB(k0 + 32); }
    bf16x8 af[4], bfr[4];
    #pragma unroll
    for (int m = 0; m < 4; ++m)
      af[m] = *(const bf16x8*)((const char*)As + lds_swz(wr + m * 16 + l15, lk16));
    #pragma unroll
    for (int n = 0; n < 4; ++n)
      bfr[n] = *(const bf16x8*)((const char*)Bs + lds_swz(wc + n * 16 + l15, lk16));
    #pragma unroll
    for (int m = 0; m < 4; ++m)
      #pragma unroll
      for (int n = 0; n < 4; ++n)
        acc[m][n] = __builtin_amdgcn_mfma_f32_16x16x32_bf16(af[m], bfr[n], acc[m][n], 0, 0, 0);
  }

  #pragma unroll
  for (int m = 0; m < 4; ++m) {
    const int rbase = row0 + wr + m * 16 + (lane >> 4) * 4;
    #pragma unroll
    for (int n = 0; n < 4; ++n) {
      const int col = col0 + wc + n * 16 + l15;
      #pragma unroll
      for (int j = 0; j < 4; ++j) {
        const int r = rbase + j;
        if (c_mode == 1)
          C[((size_t)(col >> 12) * 256 + r) * 4096 + (col & 4095)] = acc[m][n][j];
        else
          C[(size_t)r * ldc + col] = acc[m][n][j];
      }
    }
  }
}

// blocks 0..511: img out (A=W, B=H_img, NCHW store); 512..639: cls out
__global__ __launch_bounds__(256) void outproj_k(
    const ushort* __restrict__ Wimg, const ushort* __restrict__ Himg,
    float* __restrict__ Oimg, const ushort* __restrict__ Hcls,
    const ushort* __restrict__ Wcls, float* __restrict__ Ocls) {
  __shared__ char ldsb[16384];
  const int bx = blockIdx.x;
  if (bx < 512)
    mgemm_body(Wimg, Himg, Oimg, 256, 0, 1, (bx & 1) * 128, (bx >> 1) * 128, ldsb);
  else {
    const int b2 = bx - 512;
    mgemm_body(Hcls, Wcls, Ocls, 256, 256, 2, (b2 >> 1) * 128, (b2 & 1) * 128, ldsb);
  }
}

extern "C" void kernel_launch(void* const* d_in, const int* in_sizes, int n_in,
                              void* d_out, int out_size, void* d_ws, size_t ws_size,
                              hipStream_t stream) {
  const float* x        = (const float*)d_in[0];
  const float* class_x  = (const float*)d_in[1];
  const float* ea_c2i   = (const float*)d_in[2];
  const float* ea_i2c   = (const float*)d_in[3];
  const int* src_c2i = (const int*)d_in[16];
  const int* dst_c2i = (const int*)d_in[17];
  const int* src_i2c = (const int*)d_in[18];
  const int* dst_i2c = (const int*)d_in[19];

  float* ws = (float*)d_ws;
  size_t off = 0;
  auto alloc = [&](size_t n) { float* p = ws + off; off += (n + 15) & ~(size_t)15; return p; };

  ushort* A_img   = (ushort*)alloc((size_t)NIMG * 128);   // bf16 [NIMG,256] activations
  ushort* A_cls   = (ushort*)alloc((size_t)NCLS * 128);
  ushort* H_img   = (ushort*)alloc((size_t)NIMG * 128);   // layer-2 normed outputs
  ushort* H_cls   = (ushort*)alloc((size_t)NCLS * 128);
  ushort* agg_img = (ushort*)alloc((size_t)NIMG * 128);   // bf16 [NIMG,256] H-mean
  ushort* agg_cls = (ushort*)alloc((size_t)NCLS * 128);
  ushort* eam_img = (ushort*)alloc((size_t)NIMG * 32);    // bf16 [NIMG,64] EA-mean
  ushort* eam_cls = (ushort*)alloc((size_t)NCLS * 32);
  int* cnt       = (int*)alloc(2 * (NIMG + NCLS));        // cnt | cur (one memset)
  int* cur       = cnt + (NIMG + NCLS);
  int* bsum      = (int*)alloc(48);
  int* st_img    = (int*)alloc(NIMG + 1 + NCLS + 1 + 14);
  int* st_cls    = st_img + NIMG + 1;
  int2* eix_c2i  = (int2*)alloc((size_t)NE * 2);          // {edge, src}
  int2* eix_i2c  = (int2*)alloc((size_t)NE * 2);
  ushort* wn_in_img  = (ushort*)alloc(256 * 96);
  ushort* wn_in_cls  = (ushort*)alloc(256 * 64);
  ushort* wcat0      = (ushort*)alloc(256 * 288);
  ushort* wcat1      = (ushort*)alloc(256 * 288);
  ushort* wcat2      = (ushort*)alloc(256 * 288);
  ushort* wcat3      = (ushort*)alloc(256 * 288);
  ushort* wn_out_img = (ushort*)alloc(256 * 128);
  ushort* wn_out_cls = (ushort*)alloc(256 * 128);

  const dim3 blk(256);

  // ---- prologue: memset + (wnorm | counti) ----
  hipMemsetAsync(cnt, 0, (size_t)2 * (NIMG + NCLS) * sizeof(int), stream);
  WNA wa;
  const float* wsrc[12] = { (const float*)d_in[4], (const float*)d_in[5],
                            (const float*)d_in[6], (const float*)d_in[7],
                            (const float*)d_in[8], (const float*)d_in[9],
                            (const float*)d_in[10], (const float*)d_in[11],
                            (const float*)d_in[12], (const float*)d_in[13],
                            (const float*)d_in[14], (const float*)d_in[15] };
  ushort* wdst[12] = { wn_in_img, wn_in_cls, wcat0, wcat0, wcat1, wcat1,
                       wcat2, wcat2, wcat3, wcat3, wn_out_img, wn_out_cls };
  const int wF[12]  = { 192, 128, 320, 256, 320, 256, 320, 256, 320, 256, 256, 256 };
  const int wOS[12] = { 192, 128, 576, 576, 576, 576, 576, 576, 576, 576, 256, 256 };
  const int wOO[12] = { 0, 0, 0, 320, 0, 320, 0, 320, 0, 320, 0, 0 };
  for (int i = 0; i < 12; ++i) {
    wa.w[i] = wsrc[i]; wa.o[i] = wdst[i]; wa.F[i] = wF[i]; wa.os[i] = wOS[i]; wa.oo[i] = wOO[i];
  }
  pre_k<<<768 + NE / 256, blk, 0, stream>>>(wa, dst_c2i, dst_i2c, cnt, cnt + NIMG);

  // ---- CSR scan + fill ----
  scanA_k<<<40, blk, 0, stream>>>(cnt, st_img, st_cls, bsum);
  scanC_k<<<40, blk, 0, stream>>>(bsum, st_img, st_cls);
  fill2_k<<<NE / 256, blk, 0, stream>>>(dst_c2i, src_c2i, st_img, cur, eix_c2i,
                                        dst_i2c, src_i2c, st_cls, cur + NIMG, eix_i2c);

  // ---- input projections (img + cls in one launch), emit silu'd A ----
  FJ jin0 = { nullptr, nullptr, nullptr, x,       wn_in_img, A_img, 192, 1, 0, 1 };
  FJ jin1 = { nullptr, nullptr, nullptr, class_x, wn_in_cls, A_cls, 128, 3, 0, 1 };
  fgemm2_k<<<NIMG / 128 + NCLS / 128, 512, 0, stream>>>(jin0, jin1, NIMG / 128);

  // ---- layer 1: agg (+eam) -> conv (norm+silu, in-place) ----
  agg2_k<<<(NIMG + NCLS) / 4, blk, 0, stream>>>(A_img, A_cls, eix_c2i, eix_i2c,
                                                st_img, st_cls, agg_img, agg_cls,
                                                ea_c2i, ea_i2c, eam_img, eam_cls, 1);
  FJ jc10 = { A_img, agg_img, eam_img, nullptr, wcat0, A_img, 576, 2, 1, 1 };
  FJ jc11 = { A_cls, agg_cls, eam_cls, nullptr, wcat1, A_cls, 576, 2, 1, 1 };
  fgemm2_k<<<NIMG / 128 + NCLS / 128, 512, 0, stream>>>(jc10, jc11, NIMG / 128);

  // ---- layer 2: agg -> conv (norm, H out) ----
  agg2_k<<<(NIMG + NCLS) / 4, blk, 0, stream>>>(A_img, A_cls, eix_c2i, eix_i2c,
                                                st_img, st_cls, agg_img, agg_cls,
                                                nullptr, nullptr, nullptr, nullptr, 0);
  FJ jc20 = { A_img, agg_img, eam_img, nullptr, wcat2, H_img, 576, 2, 1, 0 };
  FJ jc21 = { A_cls, agg_cls, eam_cls, nullptr, wcat3, H_cls, 576, 2, 1, 0 };
  fgemm2_k<<<NIMG / 128 + NCLS / 128, 512, 0, stream>>>(jc20, jc21, NIMG / 128);

  // ---- output projections (img + cls in one launch) ----
  float* out_img = (float*)d_out;
  float* out_cls = (float*)d_out + (size_t)NIMG * 256;
  outproj_k<<<640, blk, 0, stream>>>(wn_out_img, H_img, out_img,
                                     H_cls, wn_out_cls, out_cls);
}